// Round 15
// baseline (1941.478 us; speedup 1.0000x reference)
//
#include <hip/hip_runtime.h>
#include <cfloat>

// ---- problem dims ----
#define NN    16380
#define RR    819
#define APR   20
#define KNB   16
#define HID   64
#define LAYERS 6
#define BINS  100
#define N64   (NN*HID)

// ---- geometry ----
#define ATB   32
#define NBLK  512               // 512*32 = 16384 >= NN ; 2 blocks/CU (78KB LDS) -> all co-resident
#define LDA   68
#define LDU   132
#define CSIZE 4.375f            // 70/16

// ---- workspace float offsets ----
#define OFF_QA    0
#define OFF_KA    (1*N64)
#define OFF_FA    (2*N64)
#define OFF_QB    (3*N64)
#define OFF_KB    (4*N64)
#define OFF_FB    (5*N64)
#define OFF_VA    (6*N64)           // 3 planes
#define OFF_VB    (9*N64)           // 3 planes
#define OFF_S     (12*N64)
#define OFF_DIRNS (13*N64)          // N*48 (sorted space)
#define OFF_C4    (OFF_DIRNS + NN*48)
#define OFF_C4S   (OFF_C4 + NN*4)
#define OFF_RES   (OFF_C4S + NN*4)
#define OFF_NBRS  (OFF_RES + RR*64)    // int N*16 (sorted space)
#define OFF_BINSS (OFF_NBRS + NN*16)   // int N*16
#define OFF_O2N   (OFF_BINSS + NN*16)  // int N
#define OFF_N2O   (OFF_O2N + NN)       // int N
#define OFF_CELL  (OFF_N2O + NN)       // int N
#define OFF_HIST  (OFF_CELL + NN)      // int 4096
#define OFF_CNT   (OFF_HIST + 4096)    // int 4096
#define OFF_BASE  (OFF_CNT + 4096)     // int 4096
#define OFF_BAR   (OFF_BASE + 4096)    // 2 unsigned (memset'd with hist/cnt/base)

typedef unsigned long long u64;
#define U64MAX 0xFFFFFFFFFFFFFFFFull

__device__ __forceinline__ float gelu_f(float x) {
    float x3 = x*x*x;
    float t = tanhf(0.7978845608028654f*(x + 0.044715f*x3));
    return 0.5f*x*(1.0f+t);
}
__device__ __forceinline__ float sigmoid_f(float x) {
    return 1.0f/(1.0f + expf(-x));
}
__device__ __forceinline__ int spread3(int x) {   // 4-bit -> every 3rd bit
    return (x&1) | ((x&2)<<2) | ((x&4)<<4) | ((x&8)<<6);
}
__device__ __forceinline__ unsigned sortable_u32(float f) {
    unsigned u = __float_as_uint(f);
    return u ^ ((u & 0x80000000u) ? 0xFFFFFFFFu : 0x80000000u);
}

// ---------------- fused pad + cell-id + histogram + resb zero ----------------
__global__ void pad_cell_kernel(const float* __restrict__ coords, float4* __restrict__ c4,
                                int* __restrict__ cellid, int* __restrict__ hist,
                                float* __restrict__ resb, int n) {
    int i = blockIdx.x*256 + threadIdx.x;
    for (int j = i; j < RR*HID; j += 16384) resb[j] = 0.f;
    if (i >= n) return;
    float x = coords[3*i], y = coords[3*i+1], z = coords[3*i+2];
    float sq = __fadd_rn(__fadd_rn(__fmul_rn(x,x), __fmul_rn(y,y)), __fmul_rn(z,z));
    c4[i] = make_float4(x, y, z, sq);
    int cx = min(15, max(0, (int)(x * (16.0f/70.0f))));
    int cy = min(15, max(0, (int)(y * (16.0f/70.0f))));
    int cz = min(15, max(0, (int)(z * (16.0f/70.0f))));
    int m = spread3(cx) | (spread3(cy)<<1) | (spread3(cz)<<2);
    cellid[i] = m;
    atomicAdd(&hist[m], 1);
}
__global__ void scan_kernel(const int* __restrict__ hist, int* __restrict__ base) {
    __shared__ int part[256];
    int t = threadIdx.x;
    int loc[16]; int s = 0;
    #pragma unroll
    for (int e = 0; e < 16; ++e) { loc[e] = s; s += hist[t*16+e]; }
    part[t] = s;
    __syncthreads();
    if (t == 0) { int acc = 0; for (int i = 0; i < 256; ++i) { int v = part[i]; part[i] = acc; acc += v; } }
    __syncthreads();
    int off = part[t];
    #pragma unroll
    for (int e = 0; e < 16; ++e) base[t*16+e] = off + loc[e];
}
__global__ void scatter_kernel(const int* __restrict__ cellid, const int* __restrict__ base,
                               int* __restrict__ cnt, int* __restrict__ o2n,
                               int* __restrict__ n2o, const float4* __restrict__ c4,
                               float4* __restrict__ c4s, int n) {
    int i = blockIdx.x*256 + threadIdx.x;
    if (i >= n) return;
    int m = cellid[i];
    int pos = base[m] + atomicAdd(&cnt[m], 1);
    o2n[i] = pos; n2o[pos] = i;
    c4s[pos] = c4[i];
}

// ---------------- grid kNN (round-13 verbatim) ----------------
#define SCRATCH 1024
__global__ __launch_bounds__(256) void knn_grid_kernel(
    const float4* __restrict__ c4s, const int* __restrict__ base, const int* __restrict__ hist,
    const int* __restrict__ n2o, const int* __restrict__ o2n,
    int* __restrict__ nbr, int* __restrict__ binsO, float* __restrict__ dirn, int n)
{
    __shared__ int sIdx[4][SCRATCH];
    int tid = threadIdx.x;
    int wv = tid >> 6, lane = tid & 63;
    int i = blockIdx.x*4 + wv;
    bool valid = i < n;
    int ii = valid ? i : 0;
    float4 cd = c4s[ii];
    float sqd = cd.w;
    int cx = min(15, max(0, (int)(cd.x * (16.0f/70.0f))));
    int cy = min(15, max(0, (int)(cd.y * (16.0f/70.0f))));
    int cz = min(15, max(0, (int)(cd.z * (16.0f/70.0f))));
    u64 dlist = U64MAX;
    u64 vmax  = U64MAX;
    int* sidx = sIdx[wv];

    auto compute_pk = [&](int idx) -> u64 {
        if (idx == i) return U64MAX;
        float4 cc = c4s[idx];
        float dt = __fmul_rn(cd.x, cc.x);
        dt = __fmaf_rn(cd.y, cc.y, dt);
        dt = __fmaf_rn(cd.z, cc.z, dt);
        float key = __fsub_rn(__fadd_rn(sqd, cc.w), __fmul_rn(2.0f, dt));
        int org = n2o[idx];
        return ((u64)sortable_u32(key) << 32) | (unsigned)org;
    };

    auto process_batch = [&](int M) {
        if (M <= 0) return;
        u64 lmin = U64MAX;
        for (int p = lane; p < M; p += 64) {
            u64 pk = compute_pk(sidx[p]);
            lmin = (pk < lmin) ? pk : lmin;
        }
        u64 T = lmin;
        #pragma unroll
        for (int off = 1; off < 64; off <<= 1) {
            u64 o = __shfl_xor(T, off);
            T = (o > T) ? o : T;
        }
        for (int c0 = 0; c0 < M; c0 += 64) {
            int p = c0 + lane;
            u64 mypk = (p < M) ? compute_pk(sidx[p]) : U64MAX;
            u64 bound = (vmax < T) ? vmax : T;
            unsigned long long mask = __ballot(mypk <= bound);
            while (mask) {
                int lb = (int)__builtin_ctzll(mask);
                mask &= mask - 1;
                u64 dc = __shfl(mypk, lb);
                if (dc < vmax) {
                    u64 dp = __shfl_up(dlist, 1);
                    bool below = dc < dlist;
                    bool take  = below && (lane == 0 || dc >= dp);
                    if (lane < 16) dlist = below ? (take ? dc : dp) : dlist;
                    vmax = __shfl(dlist, 15);
                }
            }
        }
    };

    for (int R = 2; R <= 16; ++R) {
        int side = 2*R+1;
        int ncell = side*side*side;
        int M = 0;
        for (int t0 = 0; t0 < ncell; t0 += 64) {
            int t = t0 + lane;
            int cnt = 0, b = 0;
            if (t < ncell) {
                int dxc = t % side - R;
                int dyc = (t/side) % side - R;
                int dzc = t/(side*side) - R;
                int ch = max(abs(dxc), max(abs(dyc), abs(dzc)));
                bool use = (R == 2) || (ch == R);
                int x = cx+dxc, y = cy+dyc, z = cz+dzc;
                if (use && x>=0 && x<16 && y>=0 && y<16 && z>=0 && z<16) {
                    int m = spread3(x) | (spread3(y)<<1) | (spread3(z)<<2);
                    cnt = hist[m]; b = base[m];
                }
            }
            int incl = cnt;
            #pragma unroll
            for (int o = 1; o < 64; o <<= 1) { int v = __shfl_up(incl, o); if (lane >= o) incl += v; }
            int excl = incl - cnt;
            int tot = __shfl(incl, 63);
            if (M + tot > SCRATCH) { process_batch(M); M = 0; }
            for (int e = 0; e < cnt; ++e) {
                int pos = M + excl + e;
                if (pos < SCRATCH) sidx[pos] = b + e;
            }
            M = min(M + tot, SCRATCH);
        }
        process_batch(M);
        float rim = (float)R * CSIZE;
        unsigned thS = sortable_u32(rim*rim - 0.05f);
        if ((unsigned)(vmax >> 32) < thS) break;
    }
    if (valid && lane < 16) {
        int org = (int)(dlist & 0xFFFFFFFFull);
        int src = o2n[org];
        float4 cs = c4s[src];
        float dx = __fsub_rn(cd.x, cs.x);
        float dy = __fsub_rn(cd.y, cs.y);
        float dz = __fsub_rn(cd.z, cs.z);
        float ss = __fadd_rn(__fadd_rn(__fmul_rn(dx,dx), __fmul_rn(dy,dy)),
                             __fmul_rn(dz,dz));
        float dd = __fsqrt_rn(__fadd_rn(ss, 1e-12f));
        nbr[i*KNB + lane] = src;
        float bf = __fmul_rn(__fdiv_rn(dd, 10.0f), 100.0f);
        int b = (int)bf;
        b = min(max(b, 0), BINS-1);
        binsO[i*KNB + lane] = b;
        dirn[i*48 + lane*3 + 0] = __fdiv_rn(dx, dd);
        dirn[i*48 + lane*3 + 1] = __fdiv_rn(dy, dd);
        dirn[i*48 + lane*3 + 2] = __fdiv_rn(dz, dd);
    }
}

// ---------------- persistent mega kernel: prologue + 6 layers + head ----------------
// Round-13 prologue/layer/head bodies verbatim; dispatch boundaries replaced by
// device-scope grid barriers. 512 blocks x 78KB LDS = exactly 2 blocks/CU on all
// 256 CUs -> all blocks co-resident -> barrier cannot deadlock.
__global__ __launch_bounds__(256) void mega_kernel(
    const int* __restrict__ aid, const int* __restrict__ rid, const int* __restrict__ eid,
    const int* __restrict__ n2o, const int* __restrict__ ridx,
    const float* __restrict__ ea, const float* __restrict__ er, const float* __restrict__ ee,
    const float* __restrict__ Win, const float* __restrict__ Wq, const float* __restrict__ Wk,
    const float* __restrict__ Wv, const float* __restrict__ Wvec, const float* __restrict__ wdir,
    const float* __restrict__ dist_bias, const float* __restrict__ Wo,
    const float* __restrict__ W1, const float* __restrict__ W2, const float* __restrict__ Wg,
    const float* __restrict__ Wout, const float* __restrict__ bout,
    float* __restrict__ qA, float* __restrict__ kA, float* __restrict__ fA,
    float* __restrict__ qB, float* __restrict__ kB, float* __restrict__ fB,
    float* __restrict__ vA, float* __restrict__ vB,
    float* __restrict__ sg, const float* __restrict__ dirn,
    const int* __restrict__ nbr, const int* __restrict__ bins,
    float* __restrict__ resb, unsigned* __restrict__ bar, float* __restrict__ out)
{
    __shared__ __align__(16) float sS[ATB*LDA];
    __shared__ __align__(16) float sH[ATB*LDA];
    __shared__ __align__(16) float sM[ATB*LDU];
    __shared__ __align__(16) float sVA[3][ATB*LDA];
    __shared__ __align__(16) float sW[4096];
    __shared__ float sDS[ATB*24];

    const int tid = threadIdx.x;
    // XCD-aware swizzle (round-13): contiguous Morton span per XCD
    const int bswz = (blockIdx.x & 7) * (NBLK/8) + (blockIdx.x >> 3);
    const int a0 = bswz*ATB;
    const int gi = tid>>4, gj = tid&15;
    const int lrow = tid>>3, lsub = tid&7;
    const int wv = tid>>6, lane = tid&63;

    auto stageW = [&](const float* W) {
        const float4* src = (const float4*)W; float4* dst = (float4*)sW;
        #pragma unroll
        for (int r = 0; r < 4; ++r) dst[tid + 256*r] = src[tid + 256*r];
    };
    auto stageW1h = [&](const float* W1l, int h) {
        const float4* src = (const float4*)W1l; float4* dst = (float4*)sW;
        #pragma unroll
        for (int r = 0; r < 4; ++r) {
            int q = tid + 256*r;
            int row = q >> 4, c4i = q & 15;
            dst[q] = src[row*32 + h*16 + c4i];
        }
    };
    auto do_gemm = [&](const float* sA, int lda, int ko, float4& c0, float4& c1) {
        const float* a0p = sA + gi*lda + ko;
        const float* a1p = sA + (gi+16)*lda + ko;
        const float* wr  = sW + gj*4;
        #pragma unroll 8
        for (int k = 0; k < 64; ++k) {
            float av0 = a0p[k], av1 = a1p[k];
            float4 w = *(const float4*)(wr + k*64);
            c0.x = fmaf(av0,w.x,c0.x); c0.y = fmaf(av0,w.y,c0.y);
            c0.z = fmaf(av0,w.z,c0.z); c0.w = fmaf(av0,w.w,c0.w);
            c1.x = fmaf(av1,w.x,c1.x); c1.y = fmaf(av1,w.y,c1.y);
            c1.z = fmaf(av1,w.z,c1.z); c1.w = fmaf(av1,w.w,c1.w);
        }
    };
    auto do_ln = [&](const float* src, float* dst) {
        const float* sp = src + lrow*LDA + lsub*8;
        float v[8]; float s1 = 0.f;
        #pragma unroll
        for (int e = 0; e < 8; ++e) { v[e] = sp[e]; s1 += v[e]; }
        s1 += __shfl_xor(s1,1); s1 += __shfl_xor(s1,2); s1 += __shfl_xor(s1,4);
        float mean = s1*(1.0f/64.0f);
        float s2 = 0.f;
        #pragma unroll
        for (int e = 0; e < 8; ++e) { float t = v[e]-mean; s2 += t*t; }
        s2 += __shfl_xor(s2,1); s2 += __shfl_xor(s2,2); s2 += __shfl_xor(s2,4);
        float sc = 1.0f/sqrtf(s2*(1.0f/64.0f)+1e-5f);
        float* dp = dst + lrow*LDA + lsub*8;
        #pragma unroll
        for (int e = 0; e < 8; ++e) dp[e] = (v[e]-mean)*sc;
    };
    auto store_g = [&](float* base, float4 c0, float4 c1) {
        int g0 = a0+gi, g1 = a0+gi+16;
        if (g0 < NN) *(float4*)(base + (size_t)g0*64 + gj*4) = c0;
        if (g1 < NN) *(float4*)(base + (size_t)g1*64 + gj*4) = c1;
    };
    auto grid_sync = [&]() {
        __syncthreads();
        __threadfence();
        if (tid == 0) {
            unsigned* cnt = bar; unsigned* gen = bar+1;
            unsigned g = __hip_atomic_load(gen, __ATOMIC_RELAXED, __HIP_MEMORY_SCOPE_AGENT);
            unsigned arr = __hip_atomic_fetch_add(cnt, 1u, __ATOMIC_ACQ_REL, __HIP_MEMORY_SCOPE_AGENT);
            if (arr == (unsigned)(NBLK-1)) {
                __hip_atomic_store(cnt, 0u, __ATOMIC_RELAXED, __HIP_MEMORY_SCOPE_AGENT);
                __hip_atomic_fetch_add(gen, 1u, __ATOMIC_RELEASE, __HIP_MEMORY_SCOPE_AGENT);
            } else {
                while (__hip_atomic_load(gen, __ATOMIC_ACQUIRE, __HIP_MEMORY_SCOPE_AGENT) == g) {}
            }
        }
        __syncthreads();
        __threadfence();
    };

    // ================= prologue phase (round-13 body) =================
    {
        int ga = a0 + lrow;
        int io = (ga < NN) ? n2o[ga] : 0;
        #pragma unroll
        for (int e = 0; e < 8; ++e) {
            int c = lsub*8 + e;
            float x = 0.f;
            if (ga < NN) {
                if (c < 32)      x = ea[aid[io]*32 + c];
                else if (c < 48) x = er[rid[io]*16 + (c-32)];
                else             x = ee[eid[io]*16 + (c-48)];
            }
            sH[lrow*LDA + c] = x;
        }
    }
    __syncthreads();
    stageW(Win); __syncthreads();
    {
        float4 c0 = make_float4(0,0,0,0), c1 = c0;
        do_gemm(sH, LDA, 0, c0, c1);
        *(float4*)(sS + gi*LDA + gj*4)      = c0;
        *(float4*)(sS + (gi+16)*LDA + gj*4) = c1;
        store_g(sg, c0, c1);
    }
    __syncthreads();
    do_ln(sS, sH);
    __syncthreads();
    stageW(Wk); __syncthreads();
    { float4 c0 = make_float4(0,0,0,0), c1 = c0; do_gemm(sH, LDA, 0, c0, c1); store_g(kA, c0, c1); }
    __syncthreads();
    stageW(Wv); __syncthreads();
    { float4 c0 = make_float4(0,0,0,0), c1 = c0; do_gemm(sH, LDA, 0, c0, c1); store_g(fA, c0, c1); }
    __syncthreads();
    stageW(Wq); __syncthreads();
    { float4 c0 = make_float4(0,0,0,0), c1 = c0; do_gemm(sH, LDA, 0, c0, c1); store_g(qA, c0, c1); }

    grid_sync();   // all q/k/vf of layer 0 visible

    // ================= layer loop (round-13 body per iteration) =================
    for (int l = 0; l < LAYERS; ++l) {
        int par = l & 1;
        const float* qin  = par ? qB : qA;
        const float* kin  = par ? kB : kA;
        const float* vfin = par ? fB : fA;
        float* qout = par ? qA : qB;
        float* kout = par ? kA : kB;
        float* vfout= par ? fA : fB;
        const float* vin = par ? vB : vA;
        float* vout      = par ? vA : vB;

        const float* Wo_l = Wo + l*4096;
        const float* Wg_l = Wg + l*4096;
        const float* Wc_l = Wvec + l*4096;
        const float* W1_l = W1 + l*8192;
        const float* W2_l = W2 + l*8192;
        const float* db_l = dist_bias + l*BINS*8;
        const float* wd_l = wdir + l*64;

        // ---- P0: load s ----
        {
            int ga = a0 + lrow;
            float4 z = make_float4(0,0,0,0);
            float4 x0 = z, x1 = z;
            if (ga < NN) {
                const float4* sp = (const float4*)(sg + (size_t)ga*64);
                x0 = sp[lsub*2]; x1 = sp[lsub*2+1];
            }
            float4* dp = (float4*)(sS + lrow*LDA);
            dp[lsub*2] = x0; dp[lsub*2+1] = x1;
        }

        // ---- P1: attention ----
        for (int aa = 0; aa < 8; ++aa) {
            int la = wv*8 + aa;
            int ga = a0 + la;
            if (ga >= NN) break;
            float qh = qin[(size_t)ga*64 + lane];
            float lg[KNB]; int nb[KNB];
            #pragma unroll
            for (int k = 0; k < KNB; ++k) {
                int j = nbr[ga*KNB + k];
                nb[k] = j;
                float t = qh * kin[(size_t)j*64 + lane];
                t += __shfl_xor(t,1); t += __shfl_xor(t,2); t += __shfl_xor(t,4);
                lg[k] = t*0.35355339059327373f + db_l[bins[ga*KNB+k]*8 + (lane>>3)];
            }
            float m = lg[0];
            #pragma unroll
            for (int k = 1; k < KNB; ++k) m = fmaxf(m, lg[k]);
            float ssum = 0.f;
            #pragma unroll
            for (int k = 0; k < KNB; ++k) { lg[k] = expf(lg[k]-m); ssum += lg[k]; }
            float inv = 1.0f/ssum;
            float mh=0.f, b0=0.f, b1=0.f, b2=0.f, s0=0.f, s1=0.f, s2=0.f;
            if (l > 0) {
                #pragma unroll
                for (int k = 0; k < KNB; ++k) {
                    float w = lg[k]*inv; int j = nb[k];
                    mh += w * vfin[(size_t)j*64 + lane];
                    b0 += w * vin[(size_t)j*64 + lane];
                    b1 += w * vin[(size_t)N64 + (size_t)j*64 + lane];
                    b2 += w * vin[2*(size_t)N64 + (size_t)j*64 + lane];
                    s0 += w * dirn[ga*48 + k*3 + 0];
                    s1 += w * dirn[ga*48 + k*3 + 1];
                    s2 += w * dirn[ga*48 + k*3 + 2];
                }
                sVA[0][la*LDA + lane] = b0;
                sVA[1][la*LDA + lane] = b1;
                sVA[2][la*LDA + lane] = b2;
            } else {
                #pragma unroll
                for (int k = 0; k < KNB; ++k) {
                    float w = lg[k]*inv; int j = nb[k];
                    mh += w * vfin[(size_t)j*64 + lane];
                    s0 += w * dirn[ga*48 + k*3 + 0];
                    s1 += w * dirn[ga*48 + k*3 + 1];
                    s2 += w * dirn[ga*48 + k*3 + 2];
                }
            }
            sM[la*LDU + lane] = mh;
            if ((lane & 7) == 0) {
                int hh = lane >> 3;
                sDS[la*24 + 0*8 + hh] = s0;
                sDS[la*24 + 1*8 + hh] = s1;
                sDS[la*24 + 2*8 + hh] = s2;
            }
        }
        __syncthreads();

        // ---- P2: s += msg @ Wo ----
        stageW(Wo_l); __syncthreads();
        {
            float4 c0 = *(float4*)(sS + gi*LDA + gj*4);
            float4 c1 = *(float4*)(sS + (gi+16)*LDA + gj*4);
            do_gemm(sM, LDU, 0, c0, c1);
            __syncthreads();
            *(float4*)(sS + gi*LDA + gj*4)      = c0;
            *(float4*)(sS + (gi+16)*LDA + gj*4) = c1;
        }
        __syncthreads();

        // ---- P3: h2 = LN(s) ----
        do_ln(sS, sH);
        __syncthreads();

        // ---- P4: gate + vector update ----
        stageW(Wg_l); __syncthreads();
        {
            float4 g0 = make_float4(0,0,0,0), g1 = g0;
            do_gemm(sH, LDA, 0, g0, g1);
            g0.x=sigmoid_f(g0.x); g0.y=sigmoid_f(g0.y); g0.z=sigmoid_f(g0.z); g0.w=sigmoid_f(g0.w);
            g1.x=sigmoid_f(g1.x); g1.y=sigmoid_f(g1.y); g1.z=sigmoid_f(g1.z); g1.w=sigmoid_f(g1.w);
            __syncthreads();
            stageW(Wc_l); __syncthreads();
            float4 wd4 = *(const float4*)&wd_l[gj*4];
            int g0i = a0+gi, g1i = a0+gi+16;
            #pragma unroll
            for (int p = 0; p < 3; ++p) {
                float4 t0 = make_float4(0,0,0,0), t1 = t0;
                if (l > 0) do_gemm(sVA[p], LDA, 0, t0, t1);
                float sp0 = sDS[gi*24 + p*8 + (gj>>1)];
                float sp1 = sDS[(gi+16)*24 + p*8 + (gj>>1)];
                if (g0i < NN) {
                    float4 vi = make_float4(0,0,0,0);
                    if (l > 0) vi = *(const float4*)(vin + (size_t)p*N64 + (size_t)g0i*64 + gj*4);
                    float4 o;
                    o.x = (vi.x + t0.x + wd4.x*sp0)*g0.x;
                    o.y = (vi.y + t0.y + wd4.y*sp0)*g0.y;
                    o.z = (vi.z + t0.z + wd4.z*sp0)*g0.z;
                    o.w = (vi.w + t0.w + wd4.w*sp0)*g0.w;
                    *(float4*)(vout + (size_t)p*N64 + (size_t)g0i*64 + gj*4) = o;
                }
                if (g1i < NN) {
                    float4 vi = make_float4(0,0,0,0);
                    if (l > 0) vi = *(const float4*)(vin + (size_t)p*N64 + (size_t)g1i*64 + gj*4);
                    float4 o;
                    o.x = (vi.x + t1.x + wd4.x*sp1)*g1.x;
                    o.y = (vi.y + t1.y + wd4.y*sp1)*g1.y;
                    o.z = (vi.z + t1.z + wd4.z*sp1)*g1.z;
                    o.w = (vi.w + t1.w + wd4.w*sp1)*g1.w;
                    *(float4*)(vout + (size_t)p*N64 + (size_t)g1i*64 + gj*4) = o;
                }
            }
        }
        __syncthreads();

        // ---- P5: FFN ----
        stageW1h(W1_l, 0); __syncthreads();
        {
            float4 c0 = make_float4(0,0,0,0), c1 = c0;
            do_gemm(sH, LDA, 0, c0, c1);
            c0.x=gelu_f(c0.x); c0.y=gelu_f(c0.y); c0.z=gelu_f(c0.z); c0.w=gelu_f(c0.w);
            c1.x=gelu_f(c1.x); c1.y=gelu_f(c1.y); c1.z=gelu_f(c1.z); c1.w=gelu_f(c1.w);
            __syncthreads();
            *(float4*)(sM + gi*LDU + gj*4)      = c0;
            *(float4*)(sM + (gi+16)*LDU + gj*4) = c1;
        }
        __syncthreads();
        stageW1h(W1_l, 1); __syncthreads();
        {
            float4 c0 = make_float4(0,0,0,0), c1 = c0;
            do_gemm(sH, LDA, 0, c0, c1);
            c0.x=gelu_f(c0.x); c0.y=gelu_f(c0.y); c0.z=gelu_f(c0.z); c0.w=gelu_f(c0.w);
            c1.x=gelu_f(c1.x); c1.y=gelu_f(c1.y); c1.z=gelu_f(c1.z); c1.w=gelu_f(c1.w);
            __syncthreads();
            *(float4*)(sM + gi*LDU + 64 + gj*4)      = c0;
            *(float4*)(sM + (gi+16)*LDU + 64 + gj*4) = c1;
        }
        __syncthreads();
        stageW(W2_l); __syncthreads();
        {
            float4 c0 = *(float4*)(sS + gi*LDA + gj*4);
            float4 c1 = *(float4*)(sS + (gi+16)*LDA + gj*4);
            do_gemm(sM, LDU, 0, c0, c1);
            __syncthreads();
            stageW(W2_l + 4096); __syncthreads();
            do_gemm(sM, LDU, 64, c0, c1);
            __syncthreads();
            *(float4*)(sS + gi*LDA + gj*4)      = c0;
            *(float4*)(sS + (gi+16)*LDA + gj*4) = c1;
        }
        __syncthreads();

        // ---- P6: next-layer q/k/vf or pooling ----
        if (l < LAYERS-1) {
            do_ln(sS, sH);
            __syncthreads();
            stageW(Wk + (l+1)*4096); __syncthreads();
            { float4 c0 = make_float4(0,0,0,0), c1 = c0; do_gemm(sH, LDA, 0, c0, c1); store_g(kout, c0, c1); }
            __syncthreads();
            stageW(Wv + (l+1)*4096); __syncthreads();
            { float4 c0 = make_float4(0,0,0,0), c1 = c0; do_gemm(sH, LDA, 0, c0, c1); store_g(vfout, c0, c1); }
            __syncthreads();
            stageW(Wq + (l+1)*4096); __syncthreads();
            { float4 c0 = make_float4(0,0,0,0), c1 = c0; do_gemm(sH, LDA, 0, c0, c1); store_g(qout, c0, c1); }
            {
                int ga = a0 + lrow;
                if (ga < NN) {
                    float4* dp = (float4*)(sg + (size_t)ga*64);
                    const float4* sp = (const float4*)(sS + lrow*LDA);
                    dp[lsub*2] = sp[lsub*2]; dp[lsub*2+1] = sp[lsub*2+1];
                }
            }
        } else {
            int ga = a0 + lrow;
            if (ga < NN) {
                int r = ridx[n2o[ga]];
                #pragma unroll
                for (int e = 0; e < 8; ++e)
                    atomicAdd(&resb[r*64 + lsub*8 + e], sS[lrow*LDA + lsub*8 + e]);
            }
        }

        grid_sync();   // layer's q/k/vf/v (or pooling) visible to all blocks
    }

    // ================= head phase (round-13 head body; first 205 blocks) =================
    {
        int r = blockIdx.x*4 + wv;
        if (blockIdx.x < (RR+3)/4 && r < RR) {
            float p = resb[r*HID + lane] * (1.0f/APR);
            float o0 = p * Wout[lane*2 + 0];
            float o1 = p * Wout[lane*2 + 1];
            #pragma unroll
            for (int off = 1; off < 64; off <<= 1) { o0 += __shfl_xor(o0, off); o1 += __shfl_xor(o1, off); }
            if (lane == 0) { out[r*2+0] = o0 + bout[0]; out[r*2+1] = o1 + bout[1]; }
        }
    }
}

// ---------------- launcher ----------------
extern "C" void kernel_launch(void* const* d_in, const int* in_sizes, int n_in,
                              void* d_out, int out_size, void* d_ws, size_t ws_size,
                              hipStream_t stream) {
    const float* coords    = (const float*)d_in[0];
    const int*   atom_ids  = (const int*)d_in[1];
    const int*   res_ids   = (const int*)d_in[2];
    const int*   elem_ids  = (const int*)d_in[3];
    const int*   ridx      = (const int*)d_in[4];
    const float* emb_atom  = (const float*)d_in[5];
    const float* emb_res   = (const float*)d_in[6];
    const float* emb_elem  = (const float*)d_in[7];
    const float* Win       = (const float*)d_in[8];
    const float* Wq        = (const float*)d_in[9];
    const float* Wk        = (const float*)d_in[10];
    const float* Wv        = (const float*)d_in[11];
    const float* Wvec      = (const float*)d_in[12];
    const float* wdir      = (const float*)d_in[13];
    const float* dist_bias = (const float*)d_in[14];
    const float* Wo        = (const float*)d_in[15];
    const float* W1        = (const float*)d_in[16];
    const float* W2        = (const float*)d_in[17];
    const float* Wg        = (const float*)d_in[18];
    const float* Wout      = (const float*)d_in[19];
    const float* bout      = (const float*)d_in[20];
    float* out = (float*)d_out;

    float* ws = (float*)d_ws;
    float* qA = ws + OFF_QA;  float* kA = ws + OFF_KA;  float* fA = ws + OFF_FA;
    float* qB = ws + OFF_QB;  float* kB = ws + OFF_KB;  float* fB = ws + OFF_FB;
    float* vA = ws + OFF_VA;  float* vB = ws + OFF_VB;
    float* sg = ws + OFF_S;
    float* dirn_s = ws + OFF_DIRNS;
    float4* c4  = (float4*)(ws + OFF_C4);
    float4* c4s = (float4*)(ws + OFF_C4S);
    float* resb = ws + OFF_RES;
    int* nbr_s  = (int*)(ws + OFF_NBRS);
    int* bins_s = (int*)(ws + OFF_BINSS);
    int* o2n    = (int*)(ws + OFF_O2N);
    int* n2o    = (int*)(ws + OFF_N2O);
    int* cellid = (int*)(ws + OFF_CELL);
    int* hist   = (int*)(ws + OFF_HIST);
    int* cnt    = (int*)(ws + OFF_CNT);
    int* baseb  = (int*)(ws + OFF_BASE);
    unsigned* bar = (unsigned*)(ws + OFF_BAR);

    // hist + cnt + base + bar contiguous: single memset zeroes all
    hipMemsetAsync(hist, 0, (3*4096 + 2)*sizeof(int), stream);

    pad_cell_kernel<<<(NN+255)/256, 256, 0, stream>>>(coords, c4, cellid, hist, resb, NN);
    scan_kernel<<<1, 256, 0, stream>>>(hist, baseb);
    scatter_kernel<<<(NN+255)/256, 256, 0, stream>>>(cellid, baseb, cnt, o2n, n2o, c4, c4s, NN);
    knn_grid_kernel<<<(NN+3)/4, 256, 0, stream>>>(c4s, baseb, hist, n2o, o2n, nbr_s, bins_s, dirn_s, NN);

    mega_kernel<<<NBLK, 256, 0, stream>>>(atom_ids, res_ids, elem_ids, n2o, ridx,
                                          emb_atom, emb_res, emb_elem,
                                          Win, Wq, Wk, Wv, Wvec, wdir, dist_bias,
                                          Wo, W1, W2, Wg, Wout, bout,
                                          qA, kA, fA, qB, kB, fB, vA, vB,
                                          sg, dirn_s, nbr_s, bins_s, resb, bar, out);
}

// Round 16
// 604.779 us; speedup vs baseline: 3.2102x; 3.2102x over previous
//
#include <hip/hip_runtime.h>
#include <cfloat>

// ---- problem dims ----
#define NN    16380
#define RR    819
#define APR   20
#define KNB   16
#define HID   64
#define LAYERS 6
#define BINS  100
#define N64   (NN*HID)

// ---- geometry ----
#define ATB   32
#define NBLK  512               // 512*32 = 16384 >= NN
#define LDA   68
#define LDU   132
#define CSIZE 4.375f            // 70/16

// ---- workspace float offsets ----
#define OFF_QA    0
#define OFF_KA    (1*N64)
#define OFF_FA    (2*N64)
#define OFF_QB    (3*N64)
#define OFF_KB    (4*N64)
#define OFF_FB    (5*N64)
#define OFF_VA    (6*N64)           // 3 planes
#define OFF_VB    (9*N64)           // 3 planes
#define OFF_S     (12*N64)
#define OFF_DIRNS (13*N64)          // N*48 (sorted space)
#define OFF_C4    (OFF_DIRNS + NN*48)
#define OFF_C4S   (OFF_C4 + NN*4)
#define OFF_RES   (OFF_C4S + NN*4)
#define OFF_NBRS  (OFF_RES + RR*64)    // int N*16 (sorted space)
#define OFF_BINSS (OFF_NBRS + NN*16)   // int N*16
#define OFF_O2N   (OFF_BINSS + NN*16)  // int N
#define OFF_N2O   (OFF_O2N + NN)       // int N
#define OFF_CELL  (OFF_N2O + NN)       // int N
#define OFF_HIST  (OFF_CELL + NN)      // int 4096
#define OFF_CNT   (OFF_HIST + 4096)    // int 4096 (adjacent: one memset covers both)
#define OFF_BASE  (OFF_CNT + 4096)     // int 4096

typedef unsigned long long u64;
#define U64MAX 0xFFFFFFFFFFFFFFFFull

__device__ __forceinline__ float gelu_f(float x) {
    float x3 = x*x*x;
    float t = tanhf(0.7978845608028654f*(x + 0.044715f*x3));
    return 0.5f*x*(1.0f+t);
}
__device__ __forceinline__ float sigmoid_f(float x) {
    return 1.0f/(1.0f + expf(-x));
}
__device__ __forceinline__ int spread3(int x) {   // 4-bit -> every 3rd bit
    return (x&1) | ((x&2)<<2) | ((x&4)<<4) | ((x&8)<<6);
}
__device__ __forceinline__ unsigned sortable_u32(float f) {
    unsigned u = __float_as_uint(f);
    return u ^ ((u & 0x80000000u) ? 0xFFFFFFFFu : 0x80000000u);
}

// ---------------- fused pad + cell-id + histogram + resb zero ----------------
__global__ void pad_cell_kernel(const float* __restrict__ coords, float4* __restrict__ c4,
                                int* __restrict__ cellid, int* __restrict__ hist,
                                float* __restrict__ resb, int n) {
    int i = blockIdx.x*256 + threadIdx.x;
    for (int j = i; j < RR*HID; j += 16384) resb[j] = 0.f;
    if (i >= n) return;
    float x = coords[3*i], y = coords[3*i+1], z = coords[3*i+2];
    float sq = __fadd_rn(__fadd_rn(__fmul_rn(x,x), __fmul_rn(y,y)), __fmul_rn(z,z));
    c4[i] = make_float4(x, y, z, sq);
    int cx = min(15, max(0, (int)(x * (16.0f/70.0f))));
    int cy = min(15, max(0, (int)(y * (16.0f/70.0f))));
    int cz = min(15, max(0, (int)(z * (16.0f/70.0f))));
    int m = spread3(cx) | (spread3(cy)<<1) | (spread3(cz)<<2);
    cellid[i] = m;
    atomicAdd(&hist[m], 1);
}
__global__ void scan_kernel(const int* __restrict__ hist, int* __restrict__ base) {
    __shared__ int part[256];
    int t = threadIdx.x;
    int loc[16]; int s = 0;
    #pragma unroll
    for (int e = 0; e < 16; ++e) { loc[e] = s; s += hist[t*16+e]; }
    part[t] = s;
    __syncthreads();
    if (t == 0) { int acc = 0; for (int i = 0; i < 256; ++i) { int v = part[i]; part[i] = acc; acc += v; } }
    __syncthreads();
    int off = part[t];
    #pragma unroll
    for (int e = 0; e < 16; ++e) base[t*16+e] = off + loc[e];
}
__global__ void scatter_kernel(const int* __restrict__ cellid, const int* __restrict__ base,
                               int* __restrict__ cnt, int* __restrict__ o2n,
                               int* __restrict__ n2o, const float4* __restrict__ c4,
                               float4* __restrict__ c4s, int n) {
    int i = blockIdx.x*256 + threadIdx.x;
    if (i >= n) return;
    int m = cellid[i];
    int pos = base[m] + atomicAdd(&cnt[m], 1);
    o2n[i] = pos; n2o[pos] = i;
    c4s[pos] = c4[i];
}

// ---------------- grid kNN: R=1 early-exit cube, then shells (order-independent) ----------------
#define SCRATCH 1024
__global__ __launch_bounds__(256) void knn_grid_kernel(
    const float4* __restrict__ c4s, const int* __restrict__ base, const int* __restrict__ hist,
    const int* __restrict__ n2o, const int* __restrict__ o2n,
    int* __restrict__ nbr, int* __restrict__ binsO, float* __restrict__ dirn, int n)
{
    __shared__ int sIdx[4][SCRATCH];
    int tid = threadIdx.x;
    int wv = tid >> 6, lane = tid & 63;
    int i = blockIdx.x*4 + wv;
    bool valid = i < n;
    int ii = valid ? i : 0;
    float4 cd = c4s[ii];
    float sqd = cd.w;
    int cx = min(15, max(0, (int)(cd.x * (16.0f/70.0f))));
    int cy = min(15, max(0, (int)(cd.y * (16.0f/70.0f))));
    int cz = min(15, max(0, (int)(cd.z * (16.0f/70.0f))));
    u64 dlist = U64MAX;
    u64 vmax  = U64MAX;
    int* sidx = sIdx[wv];

    auto compute_pk = [&](int idx) -> u64 {
        if (idx == i) return U64MAX;
        float4 cc = c4s[idx];
        float dt = __fmul_rn(cd.x, cc.x);
        dt = __fmaf_rn(cd.y, cc.y, dt);
        dt = __fmaf_rn(cd.z, cc.z, dt);
        float key = __fsub_rn(__fadd_rn(sqd, cc.w), __fmul_rn(2.0f, dt));
        int org = n2o[idx];
        return ((u64)sortable_u32(key) << 32) | (unsigned)org;
    };

    auto process_batch = [&](int M) {
        if (M <= 0) return;
        u64 lmin = U64MAX;
        for (int p = lane; p < M; p += 64) {
            u64 pk = compute_pk(sidx[p]);
            lmin = (pk < lmin) ? pk : lmin;
        }
        u64 T = lmin;
        #pragma unroll
        for (int off = 1; off < 64; off <<= 1) {
            u64 o = __shfl_xor(T, off);
            T = (o > T) ? o : T;
        }
        for (int c0 = 0; c0 < M; c0 += 64) {
            int p = c0 + lane;
            u64 mypk = (p < M) ? compute_pk(sidx[p]) : U64MAX;
            u64 bound = (vmax < T) ? vmax : T;
            unsigned long long mask = __ballot(mypk <= bound);
            while (mask) {
                int lb = (int)__builtin_ctzll(mask);
                mask &= mask - 1;
                u64 dc = __shfl(mypk, lb);
                if (dc < vmax) {
                    u64 dp = __shfl_up(dlist, 1);
                    bool below = dc < dlist;
                    bool take  = below && (lane == 0 || dc >= dp);
                    if (lane < 16) dlist = below ? (take ? dc : dp) : dlist;
                    vmax = __shfl(dlist, 15);
                }
            }
        }
    };

    // R=1: full 3x3x3 cube (early exit covers ~half the atoms);
    // R>=2: Chebyshev shell ch==R only. Union over processed R equals the
    // round-13 cell set at every termination check; selection is processing-
    // order-independent (packed lex keys), so results are bit-identical.
    for (int R = 1; R <= 16; ++R) {
        int side = 2*R+1;
        int ncell = side*side*side;
        int M = 0;
        for (int t0 = 0; t0 < ncell; t0 += 64) {
            int t = t0 + lane;
            int cnt = 0, b = 0;
            if (t < ncell) {
                int dxc = t % side - R;
                int dyc = (t/side) % side - R;
                int dzc = t/(side*side) - R;
                int ch = max(abs(dxc), max(abs(dyc), abs(dzc)));
                bool use = (R == 1) || (ch == R);
                int x = cx+dxc, y = cy+dyc, z = cz+dzc;
                if (use && x>=0 && x<16 && y>=0 && y<16 && z>=0 && z<16) {
                    int m = spread3(x) | (spread3(y)<<1) | (spread3(z)<<2);
                    cnt = hist[m]; b = base[m];
                }
            }
            int incl = cnt;
            #pragma unroll
            for (int o = 1; o < 64; o <<= 1) { int v = __shfl_up(incl, o); if (lane >= o) incl += v; }
            int excl = incl - cnt;
            int tot = __shfl(incl, 63);
            if (M + tot > SCRATCH) { process_batch(M); M = 0; }
            for (int e = 0; e < cnt; ++e) {
                int pos = M + excl + e;
                if (pos < SCRATCH) sidx[pos] = b + e;
            }
            M = min(M + tot, SCRATCH);
        }
        process_batch(M);
        float rim = (float)R * CSIZE;
        unsigned thS = sortable_u32(rim*rim - 0.05f);
        if ((unsigned)(vmax >> 32) < thS) break;
    }
    if (valid && lane < 16) {
        int org = (int)(dlist & 0xFFFFFFFFull);
        int src = o2n[org];
        float4 cs = c4s[src];
        float dx = __fsub_rn(cd.x, cs.x);
        float dy = __fsub_rn(cd.y, cs.y);
        float dz = __fsub_rn(cd.z, cs.z);
        float ss = __fadd_rn(__fadd_rn(__fmul_rn(dx,dx), __fmul_rn(dy,dy)),
                             __fmul_rn(dz,dz));
        float dd = __fsqrt_rn(__fadd_rn(ss, 1e-12f));
        nbr[i*KNB + lane] = src;
        float bf = __fmul_rn(__fdiv_rn(dd, 10.0f), 100.0f);
        int b = (int)bf;
        b = min(max(b, 0), BINS-1);
        binsO[i*KNB + lane] = b;
        dirn[i*48 + lane*3 + 0] = __fdiv_rn(dx, dd);
        dirn[i*48 + lane*3 + 1] = __fdiv_rn(dy, dd);
        dirn[i*48 + lane*3 + 2] = __fdiv_rn(dz, dd);
    }
}

// ---------------- prologue (round-13 verbatim) ----------------
__global__ __launch_bounds__(256) void prologue_kernel(
    const int* __restrict__ aid, const int* __restrict__ rid, const int* __restrict__ eid,
    const int* __restrict__ n2o,
    const float* __restrict__ ea, const float* __restrict__ er, const float* __restrict__ ee,
    const float* __restrict__ Win, const float* __restrict__ Wq, const float* __restrict__ Wk,
    const float* __restrict__ Wv,
    float* __restrict__ sg, float* __restrict__ qout, float* __restrict__ kout,
    float* __restrict__ vfout)
{
    __shared__ __align__(16) float sS[ATB*LDA];
    __shared__ __align__(16) float sH[ATB*LDA];
    __shared__ __align__(16) float sW[4096];
    const int tid = threadIdx.x;
    const int a0 = blockIdx.x*ATB;
    const int gi = tid>>4, gj = tid&15;
    const int lrow = tid>>3, lsub = tid&7;

    auto stageW = [&](const float* W) {
        const float4* src = (const float4*)W; float4* dst = (float4*)sW;
        #pragma unroll
        for (int r = 0; r < 4; ++r) dst[tid + 256*r] = src[tid + 256*r];
    };
    auto do_gemm = [&](const float* sA, float4& c0, float4& c1) {
        const float* a0p = sA + gi*LDA;
        const float* a1p = sA + (gi+16)*LDA;
        const float* wr  = sW + gj*4;
        #pragma unroll 8
        for (int k = 0; k < 64; ++k) {
            float av0 = a0p[k], av1 = a1p[k];
            float4 w = *(const float4*)(wr + k*64);
            c0.x = fmaf(av0,w.x,c0.x); c0.y = fmaf(av0,w.y,c0.y);
            c0.z = fmaf(av0,w.z,c0.z); c0.w = fmaf(av0,w.w,c0.w);
            c1.x = fmaf(av1,w.x,c1.x); c1.y = fmaf(av1,w.y,c1.y);
            c1.z = fmaf(av1,w.z,c1.z); c1.w = fmaf(av1,w.w,c1.w);
        }
    };
    auto do_ln = [&](const float* src, float* dst) {
        const float* sp = src + lrow*LDA + lsub*8;
        float v[8]; float s1 = 0.f;
        #pragma unroll
        for (int e = 0; e < 8; ++e) { v[e] = sp[e]; s1 += v[e]; }
        s1 += __shfl_xor(s1,1); s1 += __shfl_xor(s1,2); s1 += __shfl_xor(s1,4);
        float mean = s1*(1.0f/64.0f);
        float s2 = 0.f;
        #pragma unroll
        for (int e = 0; e < 8; ++e) { float t = v[e]-mean; s2 += t*t; }
        s2 += __shfl_xor(s2,1); s2 += __shfl_xor(s2,2); s2 += __shfl_xor(s2,4);
        float sc = 1.0f/sqrtf(s2*(1.0f/64.0f)+1e-5f);
        float* dp = dst + lrow*LDA + lsub*8;
        #pragma unroll
        for (int e = 0; e < 8; ++e) dp[e] = (v[e]-mean)*sc;
    };
    auto store_g = [&](float* base, float4 c0, float4 c1) {
        int g0 = a0+gi, g1 = a0+gi+16;
        if (g0 < NN) *(float4*)(base + (size_t)g0*64 + gj*4) = c0;
        if (g1 < NN) *(float4*)(base + (size_t)g1*64 + gj*4) = c1;
    };

    {
        int ga = a0 + lrow;
        int io = (ga < NN) ? n2o[ga] : 0;
        #pragma unroll
        for (int e = 0; e < 8; ++e) {
            int c = lsub*8 + e;
            float x = 0.f;
            if (ga < NN) {
                if (c < 32)      x = ea[aid[io]*32 + c];
                else if (c < 48) x = er[rid[io]*16 + (c-32)];
                else             x = ee[eid[io]*16 + (c-48)];
            }
            sH[lrow*LDA + c] = x;
        }
    }
    __syncthreads();
    stageW(Win); __syncthreads();
    {
        float4 c0 = make_float4(0,0,0,0), c1 = c0;
        do_gemm(sH, c0, c1);
        *(float4*)(sS + gi*LDA + gj*4)      = c0;
        *(float4*)(sS + (gi+16)*LDA + gj*4) = c1;
        store_g(sg, c0, c1);
    }
    __syncthreads();
    do_ln(sS, sH);
    __syncthreads();
    stageW(Wk); __syncthreads();
    { float4 c0 = make_float4(0,0,0,0), c1 = c0; do_gemm(sH, c0, c1); store_g(kout, c0, c1); }
    __syncthreads();
    stageW(Wv); __syncthreads();
    { float4 c0 = make_float4(0,0,0,0), c1 = c0; do_gemm(sH, c0, c1); store_g(vfout, c0, c1); }
    __syncthreads();
    stageW(Wq); __syncthreads();
    { float4 c0 = make_float4(0,0,0,0), c1 = c0; do_gemm(sH, c0, c1); store_g(qout, c0, c1); }
}

// ---------------- fused layer kernel (round-13 verbatim: ATB=32 + XCD swizzle) ----------------
__global__ __launch_bounds__(256) void layer_kernel(
    const float* __restrict__ qin, const float* __restrict__ kin, const float* __restrict__ vfin,
    float* __restrict__ qout, float* __restrict__ kout, float* __restrict__ vfout,
    const float* __restrict__ vin, float* __restrict__ vout,
    float* __restrict__ sg, const float* __restrict__ dirn,
    const int* __restrict__ nbr, const int* __restrict__ bins,
    float* __restrict__ resb, const int* __restrict__ ridx, const int* __restrict__ n2o,
    const float* __restrict__ Wvec, const float* __restrict__ wdir,
    const float* __restrict__ dist_bias,
    const float* __restrict__ Wo, const float* __restrict__ W1, const float* __restrict__ W2,
    const float* __restrict__ Wg, const float* __restrict__ Wq, const float* __restrict__ Wk,
    const float* __restrict__ Wv, int l)
{
    __shared__ __align__(16) float sS[ATB*LDA];
    __shared__ __align__(16) float sH[ATB*LDA];
    __shared__ __align__(16) float sM[ATB*LDU];
    __shared__ __align__(16) float sVA[3][ATB*LDA];
    __shared__ __align__(16) float sW[4096];
    __shared__ float sDS[ATB*24];

    const int tid = threadIdx.x;
    const int bswz = (blockIdx.x & 7) * (NBLK/8) + (blockIdx.x >> 3);
    const int a0 = bswz*ATB;
    const int gi = tid>>4, gj = tid&15;
    const int lrow = tid>>3, lsub = tid&7;
    const int wv = tid>>6, lane = tid&63;

    const float* Wo_l = Wo + l*4096;
    const float* Wg_l = Wg + l*4096;
    const float* Wc_l = Wvec + l*4096;
    const float* W1_l = W1 + l*8192;
    const float* W2_l = W2 + l*8192;
    const float* db_l = dist_bias + l*BINS*8;
    const float* wd_l = wdir + l*64;

    auto stageW = [&](const float* W) {
        const float4* src = (const float4*)W; float4* dst = (float4*)sW;
        #pragma unroll
        for (int r = 0; r < 4; ++r) dst[tid + 256*r] = src[tid + 256*r];
    };
    auto stageW1h = [&](const float* W1l, int h) {
        const float4* src = (const float4*)W1l; float4* dst = (float4*)sW;
        #pragma unroll
        for (int r = 0; r < 4; ++r) {
            int q = tid + 256*r;
            int row = q >> 4, c4i = q & 15;
            dst[q] = src[row*32 + h*16 + c4i];
        }
    };
    auto do_gemm = [&](const float* sA, int lda, int ko, float4& c0, float4& c1) {
        const float* a0p = sA + gi*lda + ko;
        const float* a1p = sA + (gi+16)*lda + ko;
        const float* wr  = sW + gj*4;
        #pragma unroll 8
        for (int k = 0; k < 64; ++k) {
            float av0 = a0p[k], av1 = a1p[k];
            float4 w = *(const float4*)(wr + k*64);
            c0.x = fmaf(av0,w.x,c0.x); c0.y = fmaf(av0,w.y,c0.y);
            c0.z = fmaf(av0,w.z,c0.z); c0.w = fmaf(av0,w.w,c0.w);
            c1.x = fmaf(av1,w.x,c1.x); c1.y = fmaf(av1,w.y,c1.y);
            c1.z = fmaf(av1,w.z,c1.z); c1.w = fmaf(av1,w.w,c1.w);
        }
    };
    auto do_ln = [&](const float* src, float* dst) {
        const float* sp = src + lrow*LDA + lsub*8;
        float v[8]; float s1 = 0.f;
        #pragma unroll
        for (int e = 0; e < 8; ++e) { v[e] = sp[e]; s1 += v[e]; }
        s1 += __shfl_xor(s1,1); s1 += __shfl_xor(s1,2); s1 += __shfl_xor(s1,4);
        float mean = s1*(1.0f/64.0f);
        float s2 = 0.f;
        #pragma unroll
        for (int e = 0; e < 8; ++e) { float t = v[e]-mean; s2 += t*t; }
        s2 += __shfl_xor(s2,1); s2 += __shfl_xor(s2,2); s2 += __shfl_xor(s2,4);
        float sc = 1.0f/sqrtf(s2*(1.0f/64.0f)+1e-5f);
        float* dp = dst + lrow*LDA + lsub*8;
        #pragma unroll
        for (int e = 0; e < 8; ++e) dp[e] = (v[e]-mean)*sc;
    };
    auto store_g = [&](float* base, float4 c0, float4 c1) {
        int g0 = a0+gi, g1 = a0+gi+16;
        if (g0 < NN) *(float4*)(base + (size_t)g0*64 + gj*4) = c0;
        if (g1 < NN) *(float4*)(base + (size_t)g1*64 + gj*4) = c1;
    };

    // ---- P0: load s ----
    {
        int ga = a0 + lrow;
        float4 z = make_float4(0,0,0,0);
        float4 x0 = z, x1 = z;
        if (ga < NN) {
            const float4* sp = (const float4*)(sg + (size_t)ga*64);
            x0 = sp[lsub*2]; x1 = sp[lsub*2+1];
        }
        float4* dp = (float4*)(sS + lrow*LDA);
        dp[lsub*2] = x0; dp[lsub*2+1] = x1;
    }

    // ---- P1: attention ----
    for (int aa = 0; aa < 8; ++aa) {
        int la = wv*8 + aa;
        int ga = a0 + la;
        if (ga >= NN) break;
        float qh = qin[(size_t)ga*64 + lane];
        float lg[KNB]; int nb[KNB];
        #pragma unroll
        for (int k = 0; k < KNB; ++k) {
            int j = nbr[ga*KNB + k];
            nb[k] = j;
            float t = qh * kin[(size_t)j*64 + lane];
            t += __shfl_xor(t,1); t += __shfl_xor(t,2); t += __shfl_xor(t,4);
            lg[k] = t*0.35355339059327373f + db_l[bins[ga*KNB+k]*8 + (lane>>3)];
        }
        float m = lg[0];
        #pragma unroll
        for (int k = 1; k < KNB; ++k) m = fmaxf(m, lg[k]);
        float ssum = 0.f;
        #pragma unroll
        for (int k = 0; k < KNB; ++k) { lg[k] = expf(lg[k]-m); ssum += lg[k]; }
        float inv = 1.0f/ssum;
        float mh=0.f, b0=0.f, b1=0.f, b2=0.f, s0=0.f, s1=0.f, s2=0.f;
        if (l > 0) {
            #pragma unroll
            for (int k = 0; k < KNB; ++k) {
                float w = lg[k]*inv; int j = nb[k];
                mh += w * vfin[(size_t)j*64 + lane];
                b0 += w * vin[(size_t)j*64 + lane];
                b1 += w * vin[(size_t)N64 + (size_t)j*64 + lane];
                b2 += w * vin[2*(size_t)N64 + (size_t)j*64 + lane];
                s0 += w * dirn[ga*48 + k*3 + 0];
                s1 += w * dirn[ga*48 + k*3 + 1];
                s2 += w * dirn[ga*48 + k*3 + 2];
            }
            sVA[0][la*LDA + lane] = b0;
            sVA[1][la*LDA + lane] = b1;
            sVA[2][la*LDA + lane] = b2;
        } else {
            #pragma unroll
            for (int k = 0; k < KNB; ++k) {
                float w = lg[k]*inv; int j = nb[k];
                mh += w * vfin[(size_t)j*64 + lane];
                s0 += w * dirn[ga*48 + k*3 + 0];
                s1 += w * dirn[ga*48 + k*3 + 1];
                s2 += w * dirn[ga*48 + k*3 + 2];
            }
        }
        sM[la*LDU + lane] = mh;
        if ((lane & 7) == 0) {
            int hh = lane >> 3;
            sDS[la*24 + 0*8 + hh] = s0;
            sDS[la*24 + 1*8 + hh] = s1;
            sDS[la*24 + 2*8 + hh] = s2;
        }
    }
    __syncthreads();

    // ---- P2: s += msg @ Wo ----
    stageW(Wo_l); __syncthreads();
    {
        float4 c0 = *(float4*)(sS + gi*LDA + gj*4);
        float4 c1 = *(float4*)(sS + (gi+16)*LDA + gj*4);
        do_gemm(sM, LDU, 0, c0, c1);
        __syncthreads();
        *(float4*)(sS + gi*LDA + gj*4)      = c0;
        *(float4*)(sS + (gi+16)*LDA + gj*4) = c1;
    }
    __syncthreads();

    // ---- P3: h2 = LN(s) ----
    do_ln(sS, sH);
    __syncthreads();

    // ---- P4: gate + vector update ----
    stageW(Wg_l); __syncthreads();
    {
        float4 g0 = make_float4(0,0,0,0), g1 = g0;
        do_gemm(sH, LDA, 0, g0, g1);
        g0.x=sigmoid_f(g0.x); g0.y=sigmoid_f(g0.y); g0.z=sigmoid_f(g0.z); g0.w=sigmoid_f(g0.w);
        g1.x=sigmoid_f(g1.x); g1.y=sigmoid_f(g1.y); g1.z=sigmoid_f(g1.z); g1.w=sigmoid_f(g1.w);
        __syncthreads();
        stageW(Wc_l); __syncthreads();
        float4 wd4 = *(const float4*)&wd_l[gj*4];
        int g0i = a0+gi, g1i = a0+gi+16;
        #pragma unroll
        for (int p = 0; p < 3; ++p) {
            float4 t0 = make_float4(0,0,0,0), t1 = t0;
            if (l > 0) do_gemm(sVA[p], LDA, 0, t0, t1);
            float sp0 = sDS[gi*24 + p*8 + (gj>>1)];
            float sp1 = sDS[(gi+16)*24 + p*8 + (gj>>1)];
            if (g0i < NN) {
                float4 vi = make_float4(0,0,0,0);
                if (l > 0) vi = *(const float4*)(vin + (size_t)p*N64 + (size_t)g0i*64 + gj*4);
                float4 o;
                o.x = (vi.x + t0.x + wd4.x*sp0)*g0.x;
                o.y = (vi.y + t0.y + wd4.y*sp0)*g0.y;
                o.z = (vi.z + t0.z + wd4.z*sp0)*g0.z;
                o.w = (vi.w + t0.w + wd4.w*sp0)*g0.w;
                *(float4*)(vout + (size_t)p*N64 + (size_t)g0i*64 + gj*4) = o;
            }
            if (g1i < NN) {
                float4 vi = make_float4(0,0,0,0);
                if (l > 0) vi = *(const float4*)(vin + (size_t)p*N64 + (size_t)g1i*64 + gj*4);
                float4 o;
                o.x = (vi.x + t1.x + wd4.x*sp1)*g1.x;
                o.y = (vi.y + t1.y + wd4.y*sp1)*g1.y;
                o.z = (vi.z + t1.z + wd4.z*sp1)*g1.z;
                o.w = (vi.w + t1.w + wd4.w*sp1)*g1.w;
                *(float4*)(vout + (size_t)p*N64 + (size_t)g1i*64 + gj*4) = o;
            }
        }
    }
    __syncthreads();

    // ---- P5: FFN ----
    stageW1h(W1_l, 0); __syncthreads();
    {
        float4 c0 = make_float4(0,0,0,0), c1 = c0;
        do_gemm(sH, LDA, 0, c0, c1);
        c0.x=gelu_f(c0.x); c0.y=gelu_f(c0.y); c0.z=gelu_f(c0.z); c0.w=gelu_f(c0.w);
        c1.x=gelu_f(c1.x); c1.y=gelu_f(c1.y); c1.z=gelu_f(c1.z); c1.w=gelu_f(c1.w);
        __syncthreads();
        *(float4*)(sM + gi*LDU + gj*4)      = c0;
        *(float4*)(sM + (gi+16)*LDU + gj*4) = c1;
    }
    __syncthreads();
    stageW1h(W1_l, 1); __syncthreads();
    {
        float4 c0 = make_float4(0,0,0,0), c1 = c0;
        do_gemm(sH, LDA, 0, c0, c1);
        c0.x=gelu_f(c0.x); c0.y=gelu_f(c0.y); c0.z=gelu_f(c0.z); c0.w=gelu_f(c0.w);
        c1.x=gelu_f(c1.x); c1.y=gelu_f(c1.y); c1.z=gelu_f(c1.z); c1.w=gelu_f(c1.w);
        __syncthreads();
        *(float4*)(sM + gi*LDU + 64 + gj*4)      = c0;
        *(float4*)(sM + (gi+16)*LDU + 64 + gj*4) = c1;
    }
    __syncthreads();
    stageW(W2_l); __syncthreads();
    {
        float4 c0 = *(float4*)(sS + gi*LDA + gj*4);
        float4 c1 = *(float4*)(sS + (gi+16)*LDA + gj*4);
        do_gemm(sM, LDU, 0, c0, c1);
        __syncthreads();
        stageW(W2_l + 4096); __syncthreads();
        do_gemm(sM, LDU, 64, c0, c1);
        __syncthreads();
        *(float4*)(sS + gi*LDA + gj*4)      = c0;
        *(float4*)(sS + (gi+16)*LDA + gj*4) = c1;
    }
    __syncthreads();

    // ---- P6: next-layer q/k/vf or pooling ----
    if (l < LAYERS-1) {
        do_ln(sS, sH);
        __syncthreads();
        stageW(Wk + (l+1)*4096); __syncthreads();
        { float4 c0 = make_float4(0,0,0,0), c1 = c0; do_gemm(sH, LDA, 0, c0, c1); store_g(kout, c0, c1); }
        __syncthreads();
        stageW(Wv + (l+1)*4096); __syncthreads();
        { float4 c0 = make_float4(0,0,0,0), c1 = c0; do_gemm(sH, LDA, 0, c0, c1); store_g(vfout, c0, c1); }
        __syncthreads();
        stageW(Wq + (l+1)*4096); __syncthreads();
        { float4 c0 = make_float4(0,0,0,0), c1 = c0; do_gemm(sH, LDA, 0, c0, c1); store_g(qout, c0, c1); }
        {
            int ga = a0 + lrow;
            if (ga < NN) {
                float4* dp = (float4*)(sg + (size_t)ga*64);
                const float4* sp = (const float4*)(sS + lrow*LDA);
                dp[lsub*2] = sp[lsub*2]; dp[lsub*2+1] = sp[lsub*2+1];
            }
        }
    } else {
        int ga = a0 + lrow;
        if (ga < NN) {
            int r = ridx[n2o[ga]];
            #pragma unroll
            for (int e = 0; e < 8; ++e)
                atomicAdd(&resb[r*64 + lsub*8 + e], sS[lrow*LDA + lsub*8 + e]);
        }
    }
}

// ---------------- head ----------------
__global__ void head_kernel(const float* __restrict__ res, const float* __restrict__ Wout,
                            const float* __restrict__ bout, float* __restrict__ out, int r_total) {
    int wave = threadIdx.x >> 6, lane = threadIdx.x & 63;
    int r = blockIdx.x*4 + wave;
    if (r >= r_total) return;
    float p = res[r*HID + lane] * (1.0f/APR);
    float o0 = p * Wout[lane*2 + 0];
    float o1 = p * Wout[lane*2 + 1];
    #pragma unroll
    for (int off = 1; off < 64; off <<= 1) { o0 += __shfl_xor(o0, off); o1 += __shfl_xor(o1, off); }
    if (lane == 0) { out[r*2+0] = o0 + bout[0]; out[r*2+1] = o1 + bout[1]; }
}

// ---------------- launcher ----------------
extern "C" void kernel_launch(void* const* d_in, const int* in_sizes, int n_in,
                              void* d_out, int out_size, void* d_ws, size_t ws_size,
                              hipStream_t stream) {
    const float* coords    = (const float*)d_in[0];
    const int*   atom_ids  = (const int*)d_in[1];
    const int*   res_ids   = (const int*)d_in[2];
    const int*   elem_ids  = (const int*)d_in[3];
    const int*   ridx      = (const int*)d_in[4];
    const float* emb_atom  = (const float*)d_in[5];
    const float* emb_res   = (const float*)d_in[6];
    const float* emb_elem  = (const float*)d_in[7];
    const float* Win       = (const float*)d_in[8];
    const float* Wq        = (const float*)d_in[9];
    const float* Wk        = (const float*)d_in[10];
    const float* Wv        = (const float*)d_in[11];
    const float* Wvec      = (const float*)d_in[12];
    const float* wdir      = (const float*)d_in[13];
    const float* dist_bias = (const float*)d_in[14];
    const float* Wo        = (const float*)d_in[15];
    const float* W1        = (const float*)d_in[16];
    const float* W2        = (const float*)d_in[17];
    const float* Wg        = (const float*)d_in[18];
    const float* Wout      = (const float*)d_in[19];
    const float* bout      = (const float*)d_in[20];
    float* out = (float*)d_out;

    float* ws = (float*)d_ws;
    float* qA = ws + OFF_QA;  float* kA = ws + OFF_KA;  float* fA = ws + OFF_FA;
    float* qB = ws + OFF_QB;  float* kB = ws + OFF_KB;  float* fB = ws + OFF_FB;
    float* vA = ws + OFF_VA;  float* vB = ws + OFF_VB;
    float* sg = ws + OFF_S;
    float* dirn_s = ws + OFF_DIRNS;
    float4* c4  = (float4*)(ws + OFF_C4);
    float4* c4s = (float4*)(ws + OFF_C4S);
    float* resb = ws + OFF_RES;
    int* nbr_s  = (int*)(ws + OFF_NBRS);
    int* bins_s = (int*)(ws + OFF_BINSS);
    int* o2n    = (int*)(ws + OFF_O2N);
    int* n2o    = (int*)(ws + OFF_N2O);
    int* cellid = (int*)(ws + OFF_CELL);
    int* hist   = (int*)(ws + OFF_HIST);
    int* cnt    = (int*)(ws + OFF_CNT);
    int* baseb  = (int*)(ws + OFF_BASE);

    hipMemsetAsync(hist, 0, 2*4096*sizeof(int), stream);

    pad_cell_kernel<<<(NN+255)/256, 256, 0, stream>>>(coords, c4, cellid, hist, resb, NN);
    scan_kernel<<<1, 256, 0, stream>>>(hist, baseb);
    scatter_kernel<<<(NN+255)/256, 256, 0, stream>>>(cellid, baseb, cnt, o2n, n2o, c4, c4s, NN);
    knn_grid_kernel<<<(NN+3)/4, 256, 0, stream>>>(c4s, baseb, hist, n2o, o2n, nbr_s, bins_s, dirn_s, NN);

    prologue_kernel<<<NBLK, 256, 0, stream>>>(atom_ids, res_ids, elem_ids, n2o,
                                              emb_atom, emb_res, emb_elem,
                                              Win, Wq, Wk, Wv, sg, qA, kA, fA);
    for (int l = 0; l < LAYERS; ++l) {
        int p = l & 1;
        const float* qin = p ? qB : qA;  float* qout = p ? qA : qB;
        const float* kin = p ? kB : kA;  float* kout = p ? kA : kB;
        const float* fin = p ? fB : fA;  float* fout = p ? fA : fB;
        const float* vin = p ? vB : vA;  float* vout = p ? vA : vB;
        layer_kernel<<<NBLK, 256, 0, stream>>>(qin, kin, fin, qout, kout, fout,
                                               vin, vout, sg, dirn_s, nbr_s, bins_s,
                                               resb, ridx, n2o,
                                               Wvec, wdir, dist_bias,
                                               Wo, W1, W2, Wg, Wq, Wk, Wv, l);
    }
    head_kernel<<<(RR+3)/4, 256, 0, stream>>>(resb, Wout, bout, out, RR);
}

// Round 17
// 601.054 us; speedup vs baseline: 3.2301x; 1.0062x over previous
//
#include <hip/hip_runtime.h>
#include <cfloat>

// ---- problem dims ----
#define NN    16380
#define RR    819
#define APR   20
#define KNB   16
#define HID   64
#define LAYERS 6
#define BINS  100
#define N64   (NN*HID)

// ---- geometry ----
#define ATB   32
#define NBLK  512               // 512*32 = 16384 >= NN
#define LDA   68
#define LDU   132
#define CSIZE 4.375f            // 70/16

// ---- workspace float offsets ----
#define OFF_QA    0
#define OFF_KA    (1*N64)
#define OFF_FA    (2*N64)
#define OFF_QB    (3*N64)
#define OFF_KB    (4*N64)
#define OFF_FB    (5*N64)
#define OFF_VA    (6*N64)           // 3 planes
#define OFF_VB    (9*N64)           // 3 planes
#define OFF_S     (12*N64)
#define OFF_DIRNS (13*N64)          // N*48 (sorted space)
#define OFF_C4    (OFF_DIRNS + NN*48)
#define OFF_C4S   (OFF_C4 + NN*4)
#define OFF_RES   (OFF_C4S + NN*4)
#define OFF_NBRS  (OFF_RES + RR*64)    // int N*16 (sorted space)
#define OFF_BINSS (OFF_NBRS + NN*16)   // int N*16
#define OFF_O2N   (OFF_BINSS + NN*16)  // int N
#define OFF_N2O   (OFF_O2N + NN)       // int N
#define OFF_CELL  (OFF_N2O + NN)       // int N
#define OFF_HIST  (OFF_CELL + NN)      // int 4096
#define OFF_CNT   (OFF_HIST + 4096)    // int 4096 (adjacent: one memset covers both)
#define OFF_BASE  (OFF_CNT + 4096)     // int 4096

typedef unsigned long long u64;
#define U64MAX 0xFFFFFFFFFFFFFFFFull

__device__ __forceinline__ float gelu_f(float x) {
    float x3 = x*x*x;
    float t = tanhf(0.7978845608028654f*(x + 0.044715f*x3));
    return 0.5f*x*(1.0f+t);
}
__device__ __forceinline__ float sigmoid_f(float x) {
    return 1.0f/(1.0f + expf(-x));
}
__device__ __forceinline__ int spread3(int x) {   // 4-bit -> every 3rd bit
    return (x&1) | ((x&2)<<2) | ((x&4)<<4) | ((x&8)<<6);
}
__device__ __forceinline__ unsigned sortable_u32(float f) {
    unsigned u = __float_as_uint(f);
    return u ^ ((u & 0x80000000u) ? 0xFFFFFFFFu : 0x80000000u);
}

// ---------------- fused pad + cell-id + histogram + resb zero ----------------
__global__ void pad_cell_kernel(const float* __restrict__ coords, float4* __restrict__ c4,
                                int* __restrict__ cellid, int* __restrict__ hist,
                                float* __restrict__ resb, int n) {
    int i = blockIdx.x*256 + threadIdx.x;
    for (int j = i; j < RR*HID; j += 16384) resb[j] = 0.f;
    if (i >= n) return;
    float x = coords[3*i], y = coords[3*i+1], z = coords[3*i+2];
    float sq = __fadd_rn(__fadd_rn(__fmul_rn(x,x), __fmul_rn(y,y)), __fmul_rn(z,z));
    c4[i] = make_float4(x, y, z, sq);
    int cx = min(15, max(0, (int)(x * (16.0f/70.0f))));
    int cy = min(15, max(0, (int)(y * (16.0f/70.0f))));
    int cz = min(15, max(0, (int)(z * (16.0f/70.0f))));
    int m = spread3(cx) | (spread3(cy)<<1) | (spread3(cz)<<2);
    cellid[i] = m;
    atomicAdd(&hist[m], 1);
}
__global__ void scan_kernel(const int* __restrict__ hist, int* __restrict__ base) {
    __shared__ int part[256];
    int t = threadIdx.x;
    int loc[16]; int s = 0;
    #pragma unroll
    for (int e = 0; e < 16; ++e) { loc[e] = s; s += hist[t*16+e]; }
    part[t] = s;
    __syncthreads();
    if (t == 0) { int acc = 0; for (int i = 0; i < 256; ++i) { int v = part[i]; part[i] = acc; acc += v; } }
    __syncthreads();
    int off = part[t];
    #pragma unroll
    for (int e = 0; e < 16; ++e) base[t*16+e] = off + loc[e];
}
__global__ void scatter_kernel(const int* __restrict__ cellid, const int* __restrict__ base,
                               int* __restrict__ cnt, int* __restrict__ o2n,
                               int* __restrict__ n2o, const float4* __restrict__ c4,
                               float4* __restrict__ c4s, int n) {
    int i = blockIdx.x*256 + threadIdx.x;
    if (i >= n) return;
    int m = cellid[i];
    int pos = base[m] + atomicAdd(&cnt[m], 1);
    o2n[i] = pos; n2o[pos] = i;
    c4s[pos] = c4[i];
}

// ---------------- grid kNN (round-16 verbatim: R=1 early-exit) ----------------
#define SCRATCH 1024
__global__ __launch_bounds__(256) void knn_grid_kernel(
    const float4* __restrict__ c4s, const int* __restrict__ base, const int* __restrict__ hist,
    const int* __restrict__ n2o, const int* __restrict__ o2n,
    int* __restrict__ nbr, int* __restrict__ binsO, float* __restrict__ dirn, int n)
{
    __shared__ int sIdx[4][SCRATCH];
    int tid = threadIdx.x;
    int wv = tid >> 6, lane = tid & 63;
    int i = blockIdx.x*4 + wv;
    bool valid = i < n;
    int ii = valid ? i : 0;
    float4 cd = c4s[ii];
    float sqd = cd.w;
    int cx = min(15, max(0, (int)(cd.x * (16.0f/70.0f))));
    int cy = min(15, max(0, (int)(cd.y * (16.0f/70.0f))));
    int cz = min(15, max(0, (int)(cd.z * (16.0f/70.0f))));
    u64 dlist = U64MAX;
    u64 vmax  = U64MAX;
    int* sidx = sIdx[wv];

    auto compute_pk = [&](int idx) -> u64 {
        if (idx == i) return U64MAX;
        float4 cc = c4s[idx];
        float dt = __fmul_rn(cd.x, cc.x);
        dt = __fmaf_rn(cd.y, cc.y, dt);
        dt = __fmaf_rn(cd.z, cc.z, dt);
        float key = __fsub_rn(__fadd_rn(sqd, cc.w), __fmul_rn(2.0f, dt));
        int org = n2o[idx];
        return ((u64)sortable_u32(key) << 32) | (unsigned)org;
    };

    auto process_batch = [&](int M) {
        if (M <= 0) return;
        u64 lmin = U64MAX;
        for (int p = lane; p < M; p += 64) {
            u64 pk = compute_pk(sidx[p]);
            lmin = (pk < lmin) ? pk : lmin;
        }
        u64 T = lmin;
        #pragma unroll
        for (int off = 1; off < 64; off <<= 1) {
            u64 o = __shfl_xor(T, off);
            T = (o > T) ? o : T;
        }
        for (int c0 = 0; c0 < M; c0 += 64) {
            int p = c0 + lane;
            u64 mypk = (p < M) ? compute_pk(sidx[p]) : U64MAX;
            u64 bound = (vmax < T) ? vmax : T;
            unsigned long long mask = __ballot(mypk <= bound);
            while (mask) {
                int lb = (int)__builtin_ctzll(mask);
                mask &= mask - 1;
                u64 dc = __shfl(mypk, lb);
                if (dc < vmax) {
                    u64 dp = __shfl_up(dlist, 1);
                    bool below = dc < dlist;
                    bool take  = below && (lane == 0 || dc >= dp);
                    if (lane < 16) dlist = below ? (take ? dc : dp) : dlist;
                    vmax = __shfl(dlist, 15);
                }
            }
        }
    };

    for (int R = 1; R <= 16; ++R) {
        int side = 2*R+1;
        int ncell = side*side*side;
        int M = 0;
        for (int t0 = 0; t0 < ncell; t0 += 64) {
            int t = t0 + lane;
            int cnt = 0, b = 0;
            if (t < ncell) {
                int dxc = t % side - R;
                int dyc = (t/side) % side - R;
                int dzc = t/(side*side) - R;
                int ch = max(abs(dxc), max(abs(dyc), abs(dzc)));
                bool use = (R == 1) || (ch == R);
                int x = cx+dxc, y = cy+dyc, z = cz+dzc;
                if (use && x>=0 && x<16 && y>=0 && y<16 && z>=0 && z<16) {
                    int m = spread3(x) | (spread3(y)<<1) | (spread3(z)<<2);
                    cnt = hist[m]; b = base[m];
                }
            }
            int incl = cnt;
            #pragma unroll
            for (int o = 1; o < 64; o <<= 1) { int v = __shfl_up(incl, o); if (lane >= o) incl += v; }
            int excl = incl - cnt;
            int tot = __shfl(incl, 63);
            if (M + tot > SCRATCH) { process_batch(M); M = 0; }
            for (int e = 0; e < cnt; ++e) {
                int pos = M + excl + e;
                if (pos < SCRATCH) sidx[pos] = b + e;
            }
            M = min(M + tot, SCRATCH);
        }
        process_batch(M);
        float rim = (float)R * CSIZE;
        unsigned thS = sortable_u32(rim*rim - 0.05f);
        if ((unsigned)(vmax >> 32) < thS) break;
    }
    if (valid && lane < 16) {
        int org = (int)(dlist & 0xFFFFFFFFull);
        int src = o2n[org];
        float4 cs = c4s[src];
        float dx = __fsub_rn(cd.x, cs.x);
        float dy = __fsub_rn(cd.y, cs.y);
        float dz = __fsub_rn(cd.z, cs.z);
        float ss = __fadd_rn(__fadd_rn(__fmul_rn(dx,dx), __fmul_rn(dy,dy)),
                             __fmul_rn(dz,dz));
        float dd = __fsqrt_rn(__fadd_rn(ss, 1e-12f));
        nbr[i*KNB + lane] = src;
        float bf = __fmul_rn(__fdiv_rn(dd, 10.0f), 100.0f);
        int b = (int)bf;
        b = min(max(b, 0), BINS-1);
        binsO[i*KNB + lane] = b;
        dirn[i*48 + lane*3 + 0] = __fdiv_rn(dx, dd);
        dirn[i*48 + lane*3 + 1] = __fdiv_rn(dy, dd);
        dirn[i*48 + lane*3 + 2] = __fdiv_rn(dz, dd);
    }
}

// ---------------- prologue: round-16 arithmetic, compressed barrier schedule ----------------
__global__ __launch_bounds__(256) void prologue_kernel(
    const int* __restrict__ aid, const int* __restrict__ rid, const int* __restrict__ eid,
    const int* __restrict__ n2o,
    const float* __restrict__ ea, const float* __restrict__ er, const float* __restrict__ ee,
    const float* __restrict__ Win, const float* __restrict__ Wq, const float* __restrict__ Wk,
    const float* __restrict__ Wv,
    float* __restrict__ sg, float* __restrict__ qout, float* __restrict__ kout,
    float* __restrict__ vfout)
{
    __shared__ __align__(16) float sS[ATB*LDA];
    __shared__ __align__(16) float sH[ATB*LDA];
    __shared__ __align__(16) float sW[4096];
    const int tid = threadIdx.x;
    const int a0 = blockIdx.x*ATB;
    const int gi = tid>>4, gj = tid&15;
    const int lrow = tid>>3, lsub = tid&7;

    auto stageW = [&](const float* W) {
        const float4* src = (const float4*)W; float4* dst = (float4*)sW;
        #pragma unroll
        for (int r = 0; r < 4; ++r) dst[tid + 256*r] = src[tid + 256*r];
    };
    auto do_gemm = [&](const float* sA, float4& c0, float4& c1) {
        const float* a0p = sA + gi*LDA;
        const float* a1p = sA + (gi+16)*LDA;
        const float* wr  = sW + gj*4;
        #pragma unroll 8
        for (int k = 0; k < 64; ++k) {
            float av0 = a0p[k], av1 = a1p[k];
            float4 w = *(const float4*)(wr + k*64);
            c0.x = fmaf(av0,w.x,c0.x); c0.y = fmaf(av0,w.y,c0.y);
            c0.z = fmaf(av0,w.z,c0.z); c0.w = fmaf(av0,w.w,c0.w);
            c1.x = fmaf(av1,w.x,c1.x); c1.y = fmaf(av1,w.y,c1.y);
            c1.z = fmaf(av1,w.z,c1.z); c1.w = fmaf(av1,w.w,c1.w);
        }
    };
    auto do_ln = [&](const float* src, float* dst) {
        const float* sp = src + lrow*LDA + lsub*8;
        float v[8]; float s1 = 0.f;
        #pragma unroll
        for (int e = 0; e < 8; ++e) { v[e] = sp[e]; s1 += v[e]; }
        s1 += __shfl_xor(s1,1); s1 += __shfl_xor(s1,2); s1 += __shfl_xor(s1,4);
        float mean = s1*(1.0f/64.0f);
        float s2 = 0.f;
        #pragma unroll
        for (int e = 0; e < 8; ++e) { float t = v[e]-mean; s2 += t*t; }
        s2 += __shfl_xor(s2,1); s2 += __shfl_xor(s2,2); s2 += __shfl_xor(s2,4);
        float sc = 1.0f/sqrtf(s2*(1.0f/64.0f)+1e-5f);
        float* dp = dst + lrow*LDA + lsub*8;
        #pragma unroll
        for (int e = 0; e < 8; ++e) dp[e] = (v[e]-mean)*sc;
    };
    auto store_g = [&](float* base, float4 c0, float4 c1) {
        int g0 = a0+gi, g1 = a0+gi+16;
        if (g0 < NN) *(float4*)(base + (size_t)g0*64 + gj*4) = c0;
        if (g1 < NN) *(float4*)(base + (size_t)g1*64 + gj*4) = c1;
    };

    {   // feat -> sH  (overlapped with Win staging; both guarded by next sync)
        int ga = a0 + lrow;
        int io = (ga < NN) ? n2o[ga] : 0;
        #pragma unroll
        for (int e = 0; e < 8; ++e) {
            int c = lsub*8 + e;
            float x = 0.f;
            if (ga < NN) {
                if (c < 32)      x = ea[aid[io]*32 + c];
                else if (c < 48) x = er[rid[io]*16 + (c-32)];
                else             x = ee[eid[io]*16 + (c-48)];
            }
            sH[lrow*LDA + c] = x;
        }
    }
    stageW(Win);
    __syncthreads();
    {
        float4 c0 = make_float4(0,0,0,0), c1 = c0;
        do_gemm(sH, c0, c1);
        *(float4*)(sS + gi*LDA + gj*4)      = c0;
        *(float4*)(sS + (gi+16)*LDA + gj*4) = c1;
        store_g(sg, c0, c1);
    }
    __syncthreads();                 // all done with sH(feat), sW(Win); sS written
    do_ln(sS, sH);                   // overlap LN with Wk staging
    stageW(Wk);
    __syncthreads();
    { float4 c0 = make_float4(0,0,0,0), c1 = c0; do_gemm(sH, c0, c1); store_g(kout, c0, c1); }
    __syncthreads();
    stageW(Wv); __syncthreads();
    { float4 c0 = make_float4(0,0,0,0), c1 = c0; do_gemm(sH, c0, c1); store_g(vfout, c0, c1); }
    __syncthreads();
    stageW(Wq); __syncthreads();
    { float4 c0 = make_float4(0,0,0,0), c1 = c0; do_gemm(sH, c0, c1); store_g(qout, c0, c1); }
}

// ---------------- fused layer kernel: round-16 arithmetic, compressed barrier schedule ----------------
__global__ __launch_bounds__(256) void layer_kernel(
    const float* __restrict__ qin, const float* __restrict__ kin, const float* __restrict__ vfin,
    float* __restrict__ qout, float* __restrict__ kout, float* __restrict__ vfout,
    const float* __restrict__ vin, float* __restrict__ vout,
    float* __restrict__ sg, const float* __restrict__ dirn,
    const int* __restrict__ nbr, const int* __restrict__ bins,
    float* __restrict__ resb, const int* __restrict__ ridx, const int* __restrict__ n2o,
    const float* __restrict__ Wvec, const float* __restrict__ wdir,
    const float* __restrict__ dist_bias,
    const float* __restrict__ Wo, const float* __restrict__ W1, const float* __restrict__ W2,
    const float* __restrict__ Wg, const float* __restrict__ Wq, const float* __restrict__ Wk,
    const float* __restrict__ Wv, int l)
{
    __shared__ __align__(16) float sS[ATB*LDA];
    __shared__ __align__(16) float sH[ATB*LDA];
    __shared__ __align__(16) float sM[ATB*LDU];
    __shared__ __align__(16) float sVA[3][ATB*LDA];
    __shared__ __align__(16) float sW[4096];
    __shared__ float sDS[ATB*24];

    const int tid = threadIdx.x;
    const int bswz = (blockIdx.x & 7) * (NBLK/8) + (blockIdx.x >> 3);
    const int a0 = bswz*ATB;
    const int gi = tid>>4, gj = tid&15;
    const int lrow = tid>>3, lsub = tid&7;
    const int wv = tid>>6, lane = tid&63;

    const float* Wo_l = Wo + l*4096;
    const float* Wg_l = Wg + l*4096;
    const float* Wc_l = Wvec + l*4096;
    const float* W1_l = W1 + l*8192;
    const float* W2_l = W2 + l*8192;
    const float* db_l = dist_bias + l*BINS*8;
    const float* wd_l = wdir + l*64;

    auto stageW = [&](const float* W) {
        const float4* src = (const float4*)W; float4* dst = (float4*)sW;
        #pragma unroll
        for (int r = 0; r < 4; ++r) dst[tid + 256*r] = src[tid + 256*r];
    };
    auto stageW1h = [&](const float* W1l, int h) {
        const float4* src = (const float4*)W1l; float4* dst = (float4*)sW;
        #pragma unroll
        for (int r = 0; r < 4; ++r) {
            int q = tid + 256*r;
            int row = q >> 4, c4i = q & 15;
            dst[q] = src[row*32 + h*16 + c4i];
        }
    };
    auto do_gemm = [&](const float* sA, int lda, int ko, float4& c0, float4& c1) {
        const float* a0p = sA + gi*lda + ko;
        const float* a1p = sA + (gi+16)*lda + ko;
        const float* wr  = sW + gj*4;
        #pragma unroll 8
        for (int k = 0; k < 64; ++k) {
            float av0 = a0p[k], av1 = a1p[k];
            float4 w = *(const float4*)(wr + k*64);
            c0.x = fmaf(av0,w.x,c0.x); c0.y = fmaf(av0,w.y,c0.y);
            c0.z = fmaf(av0,w.z,c0.z); c0.w = fmaf(av0,w.w,c0.w);
            c1.x = fmaf(av1,w.x,c1.x); c1.y = fmaf(av1,w.y,c1.y);
            c1.z = fmaf(av1,w.z,c1.z); c1.w = fmaf(av1,w.w,c1.w);
        }
    };
    auto do_ln = [&](const float* src, float* dst) {
        const float* sp = src + lrow*LDA + lsub*8;
        float v[8]; float s1 = 0.f;
        #pragma unroll
        for (int e = 0; e < 8; ++e) { v[e] = sp[e]; s1 += v[e]; }
        s1 += __shfl_xor(s1,1); s1 += __shfl_xor(s1,2); s1 += __shfl_xor(s1,4);
        float mean = s1*(1.0f/64.0f);
        float s2 = 0.f;
        #pragma unroll
        for (int e = 0; e < 8; ++e) { float t = v[e]-mean; s2 += t*t; }
        s2 += __shfl_xor(s2,1); s2 += __shfl_xor(s2,2); s2 += __shfl_xor(s2,4);
        float sc = 1.0f/sqrtf(s2*(1.0f/64.0f)+1e-5f);
        float* dp = dst + lrow*LDA + lsub*8;
        #pragma unroll
        for (int e = 0; e < 8; ++e) dp[e] = (v[e]-mean)*sc;
    };
    auto store_g = [&](float* base, float4 c0, float4 c1) {
        int g0 = a0+gi, g1 = a0+gi+16;
        if (g0 < NN) *(float4*)(base + (size_t)g0*64 + gj*4) = c0;
        if (g1 < NN) *(float4*)(base + (size_t)g1*64 + gj*4) = c1;
    };

    // ---- P0: load s ----
    {
        int ga = a0 + lrow;
        float4 z = make_float4(0,0,0,0);
        float4 x0 = z, x1 = z;
        if (ga < NN) {
            const float4* sp = (const float4*)(sg + (size_t)ga*64);
            x0 = sp[lsub*2]; x1 = sp[lsub*2+1];
        }
        float4* dp = (float4*)(sS + lrow*LDA);
        dp[lsub*2] = x0; dp[lsub*2+1] = x1;
    }
    // prestage Wo: sW is idle during attention; guarded by the post-attention sync
    stageW(Wo_l);

    // ---- P1: attention ----
    for (int aa = 0; aa < 8; ++aa) {
        int la = wv*8 + aa;
        int ga = a0 + la;
        if (ga >= NN) break;
        float qh = qin[(size_t)ga*64 + lane];
        float lg[KNB]; int nb[KNB];
        #pragma unroll
        for (int k = 0; k < KNB; ++k) {
            int j = nbr[ga*KNB + k];
            nb[k] = j;
            float t = qh * kin[(size_t)j*64 + lane];
            t += __shfl_xor(t,1); t += __shfl_xor(t,2); t += __shfl_xor(t,4);
            lg[k] = t*0.35355339059327373f + db_l[bins[ga*KNB+k]*8 + (lane>>3)];
        }
        float m = lg[0];
        #pragma unroll
        for (int k = 1; k < KNB; ++k) m = fmaxf(m, lg[k]);
        float ssum = 0.f;
        #pragma unroll
        for (int k = 0; k < KNB; ++k) { lg[k] = expf(lg[k]-m); ssum += lg[k]; }
        float inv = 1.0f/ssum;
        float mh=0.f, b0=0.f, b1=0.f, b2=0.f, s0=0.f, s1=0.f, s2=0.f;
        if (l > 0) {
            #pragma unroll
            for (int k = 0; k < KNB; ++k) {
                float w = lg[k]*inv; int j = nb[k];
                mh += w * vfin[(size_t)j*64 + lane];
                b0 += w * vin[(size_t)j*64 + lane];
                b1 += w * vin[(size_t)N64 + (size_t)j*64 + lane];
                b2 += w * vin[2*(size_t)N64 + (size_t)j*64 + lane];
                s0 += w * dirn[ga*48 + k*3 + 0];
                s1 += w * dirn[ga*48 + k*3 + 1];
                s2 += w * dirn[ga*48 + k*3 + 2];
            }
            sVA[0][la*LDA + lane] = b0;
            sVA[1][la*LDA + lane] = b1;
            sVA[2][la*LDA + lane] = b2;
        } else {
            #pragma unroll
            for (int k = 0; k < KNB; ++k) {
                float w = lg[k]*inv; int j = nb[k];
                mh += w * vfin[(size_t)j*64 + lane];
                s0 += w * dirn[ga*48 + k*3 + 0];
                s1 += w * dirn[ga*48 + k*3 + 1];
                s2 += w * dirn[ga*48 + k*3 + 2];
            }
        }
        sM[la*LDU + lane] = mh;
        if ((lane & 7) == 0) {
            int hh = lane >> 3;
            sDS[la*24 + 0*8 + hh] = s0;
            sDS[la*24 + 1*8 + hh] = s1;
            sDS[la*24 + 2*8 + hh] = s2;
        }
    }
    __syncthreads();   // covers: P0 sS, attention sM/sVA/sDS, Wo staging

    // ---- P2: s += msg @ Wo (own-cell read/write; no intra-phase hazard) ----
    {
        float4 c0 = *(float4*)(sS + gi*LDA + gj*4);
        float4 c1 = *(float4*)(sS + (gi+16)*LDA + gj*4);
        do_gemm(sM, LDU, 0, c0, c1);
        *(float4*)(sS + gi*LDA + gj*4)      = c0;
        *(float4*)(sS + (gi+16)*LDA + gj*4) = c1;
    }
    __syncthreads();   // sS stable; all done reading sW(Wo)

    // ---- P3: h2 = LN(s) (overlap Wg staging) ----
    do_ln(sS, sH);
    stageW(Wg_l);
    __syncthreads();

    // ---- P4: gate + vector update ----
    {
        float4 g0 = make_float4(0,0,0,0), g1 = g0;
        do_gemm(sH, LDA, 0, g0, g1);
        g0.x=sigmoid_f(g0.x); g0.y=sigmoid_f(g0.y); g0.z=sigmoid_f(g0.z); g0.w=sigmoid_f(g0.w);
        g1.x=sigmoid_f(g1.x); g1.y=sigmoid_f(g1.y); g1.z=sigmoid_f(g1.z); g1.w=sigmoid_f(g1.w);
        __syncthreads();            // all done reading sW(Wg)
        stageW(Wc_l); __syncthreads();
        float4 wd4 = *(const float4*)&wd_l[gj*4];
        int g0i = a0+gi, g1i = a0+gi+16;
        #pragma unroll
        for (int p = 0; p < 3; ++p) {
            float4 t0 = make_float4(0,0,0,0), t1 = t0;
            if (l > 0) do_gemm(sVA[p], LDA, 0, t0, t1);
            float sp0 = sDS[gi*24 + p*8 + (gj>>1)];
            float sp1 = sDS[(gi+16)*24 + p*8 + (gj>>1)];
            if (g0i < NN) {
                float4 vi = make_float4(0,0,0,0);
                if (l > 0) vi = *(const float4*)(vin + (size_t)p*N64 + (size_t)g0i*64 + gj*4);
                float4 o;
                o.x = (vi.x + t0.x + wd4.x*sp0)*g0.x;
                o.y = (vi.y + t0.y + wd4.y*sp0)*g0.y;
                o.z = (vi.z + t0.z + wd4.z*sp0)*g0.z;
                o.w = (vi.w + t0.w + wd4.w*sp0)*g0.w;
                *(float4*)(vout + (size_t)p*N64 + (size_t)g0i*64 + gj*4) = o;
            }
            if (g1i < NN) {
                float4 vi = make_float4(0,0,0,0);
                if (l > 0) vi = *(const float4*)(vin + (size_t)p*N64 + (size_t)g1i*64 + gj*4);
                float4 o;
                o.x = (vi.x + t1.x + wd4.x*sp1)*g1.x;
                o.y = (vi.y + t1.y + wd4.y*sp1)*g1.y;
                o.z = (vi.z + t1.z + wd4.z*sp1)*g1.z;
                o.w = (vi.w + t1.w + wd4.w*sp1)*g1.w;
                *(float4*)(vout + (size_t)p*N64 + (size_t)g1i*64 + gj*4) = o;
            }
        }
    }
    __syncthreads();   // all done reading sW(Wc), sVA, sDS

    // ---- P5: FFN (sM writes overlapped with the next weight staging) ----
    stageW1h(W1_l, 0); __syncthreads();
    float4 u0a, u1a;
    {
        float4 c0 = make_float4(0,0,0,0), c1 = c0;
        do_gemm(sH, LDA, 0, c0, c1);
        c0.x=gelu_f(c0.x); c0.y=gelu_f(c0.y); c0.z=gelu_f(c0.z); c0.w=gelu_f(c0.w);
        c1.x=gelu_f(c1.x); c1.y=gelu_f(c1.y); c1.z=gelu_f(c1.z); c1.w=gelu_f(c1.w);
        u0a = c0; u1a = c1;
    }
    __syncthreads();   // all done reading sW(W1h0)
    *(float4*)(sM + gi*LDU + gj*4)      = u0a;
    *(float4*)(sM + (gi+16)*LDU + gj*4) = u1a;
    stageW1h(W1_l, 1);
    __syncthreads();
    float4 u0b, u1b;
    {
        float4 c0 = make_float4(0,0,0,0), c1 = c0;
        do_gemm(sH, LDA, 0, c0, c1);
        c0.x=gelu_f(c0.x); c0.y=gelu_f(c0.y); c0.z=gelu_f(c0.z); c0.w=gelu_f(c0.w);
        c1.x=gelu_f(c1.x); c1.y=gelu_f(c1.y); c1.z=gelu_f(c1.z); c1.w=gelu_f(c1.w);
        u0b = c0; u1b = c1;
    }
    __syncthreads();   // all done reading sW(W1h1)
    *(float4*)(sM + gi*LDU + 64 + gj*4)      = u0b;
    *(float4*)(sM + (gi+16)*LDU + 64 + gj*4) = u1b;
    stageW(W2_l);
    __syncthreads();
    {
        float4 c0 = *(float4*)(sS + gi*LDA + gj*4);
        float4 c1 = *(float4*)(sS + (gi+16)*LDA + gj*4);
        do_gemm(sM, LDU, 0, c0, c1);
        __syncthreads();            // all done reading sW(W2a)
        stageW(W2_l + 4096); __syncthreads();
        do_gemm(sM, LDU, 64, c0, c1);
        *(float4*)(sS + gi*LDA + gj*4)      = c0;
        *(float4*)(sS + (gi+16)*LDA + gj*4) = c1;
    }
    __syncthreads();   // sS stable; all done reading sW(W2b), sM

    // ---- P6: next-layer q/k/vf or pooling ----
    if (l < LAYERS-1) {
        do_ln(sS, sH);
        stageW(Wk + (l+1)*4096);    // overlap with LN
        __syncthreads();
        { float4 c0 = make_float4(0,0,0,0), c1 = c0; do_gemm(sH, LDA, 0, c0, c1); store_g(kout, c0, c1); }
        __syncthreads();
        stageW(Wv + (l+1)*4096); __syncthreads();
        { float4 c0 = make_float4(0,0,0,0), c1 = c0; do_gemm(sH, LDA, 0, c0, c1); store_g(vfout, c0, c1); }
        __syncthreads();
        stageW(Wq + (l+1)*4096); __syncthreads();
        { float4 c0 = make_float4(0,0,0,0), c1 = c0; do_gemm(sH, LDA, 0, c0, c1); store_g(qout, c0, c1); }
        {
            int ga = a0 + lrow;
            if (ga < NN) {
                float4* dp = (float4*)(sg + (size_t)ga*64);
                const float4* sp = (const float4*)(sS + lrow*LDA);
                dp[lsub*2] = sp[lsub*2]; dp[lsub*2+1] = sp[lsub*2+1];
            }
        }
    } else {
        int ga = a0 + lrow;
        if (ga < NN) {
            int r = ridx[n2o[ga]];
            #pragma unroll
            for (int e = 0; e < 8; ++e)
                atomicAdd(&resb[r*64 + lsub*8 + e], sS[lrow*LDA + lsub*8 + e]);
        }
    }
}

// ---------------- head ----------------
__global__ void head_kernel(const float* __restrict__ res, const float* __restrict__ Wout,
                            const float* __restrict__ bout, float* __restrict__ out, int r_total) {
    int wave = threadIdx.x >> 6, lane = threadIdx.x & 63;
    int r = blockIdx.x*4 + wave;
    if (r >= r_total) return;
    float p = res[r*HID + lane] * (1.0f/APR);
    float o0 = p * Wout[lane*2 + 0];
    float o1 = p * Wout[lane*2 + 1];
    #pragma unroll
    for (int off = 1; off < 64; off <<= 1) { o0 += __shfl_xor(o0, off); o1 += __shfl_xor(o1, off); }
    if (lane == 0) { out[r*2+0] = o0 + bout[0]; out[r*2+1] = o1 + bout[1]; }
}

// ---------------- launcher ----------------
extern "C" void kernel_launch(void* const* d_in, const int* in_sizes, int n_in,
                              void* d_out, int out_size, void* d_ws, size_t ws_size,
                              hipStream_t stream) {
    const float* coords    = (const float*)d_in[0];
    const int*   atom_ids  = (const int*)d_in[1];
    const int*   res_ids   = (const int*)d_in[2];
    const int*   elem_ids  = (const int*)d_in[3];
    const int*   ridx      = (const int*)d_in[4];
    const float* emb_atom  = (const float*)d_in[5];
    const float* emb_res   = (const float*)d_in[6];
    const float* emb_elem  = (const float*)d_in[7];
    const float* Win       = (const float*)d_in[8];
    const float* Wq        = (const float*)d_in[9];
    const float* Wk        = (const float*)d_in[10];
    const float* Wv        = (const float*)d_in[11];
    const float* Wvec      = (const float*)d_in[12];
    const float* wdir      = (const float*)d_in[13];
    const float* dist_bias = (const float*)d_in[14];
    const float* Wo        = (const float*)d_in[15];
    const float* W1        = (const float*)d_in[16];
    const float* W2        = (const float*)d_in[17];
    const float* Wg        = (const float*)d_in[18];
    const float* Wout      = (const float*)d_in[19];
    const float* bout      = (const float*)d_in[20];
    float* out = (float*)d_out;

    float* ws = (float*)d_ws;
    float* qA = ws + OFF_QA;  float* kA = ws + OFF_KA;  float* fA = ws + OFF_FA;
    float* qB = ws + OFF_QB;  float* kB = ws + OFF_KB;  float* fB = ws + OFF_FB;
    float* vA = ws + OFF_VA;  float* vB = ws + OFF_VB;
    float* sg = ws + OFF_S;
    float* dirn_s = ws + OFF_DIRNS;
    float4* c4  = (float4*)(ws + OFF_C4);
    float4* c4s = (float4*)(ws + OFF_C4S);
    float* resb = ws + OFF_RES;
    int* nbr_s  = (int*)(ws + OFF_NBRS);
    int* bins_s = (int*)(ws + OFF_BINSS);
    int* o2n    = (int*)(ws + OFF_O2N);
    int* n2o    = (int*)(ws + OFF_N2O);
    int* cellid = (int*)(ws + OFF_CELL);
    int* hist   = (int*)(ws + OFF_HIST);
    int* cnt    = (int*)(ws + OFF_CNT);
    int* baseb  = (int*)(ws + OFF_BASE);

    hipMemsetAsync(hist, 0, 2*4096*sizeof(int), stream);

    pad_cell_kernel<<<(NN+255)/256, 256, 0, stream>>>(coords, c4, cellid, hist, resb, NN);
    scan_kernel<<<1, 256, 0, stream>>>(hist, baseb);
    scatter_kernel<<<(NN+255)/256, 256, 0, stream>>>(cellid, baseb, cnt, o2n, n2o, c4, c4s, NN);
    knn_grid_kernel<<<(NN+3)/4, 256, 0, stream>>>(c4s, baseb, hist, n2o, o2n, nbr_s, bins_s, dirn_s, NN);

    prologue_kernel<<<NBLK, 256, 0, stream>>>(atom_ids, res_ids, elem_ids, n2o,
                                              emb_atom, emb_res, emb_elem,
                                              Win, Wq, Wk, Wv, sg, qA, kA, fA);
    for (int l = 0; l < LAYERS; ++l) {
        int p = l & 1;
        const float* qin = p ? qB : qA;  float* qout = p ? qA : qB;
        const float* kin = p ? kB : kA;  float* kout = p ? kA : kB;
        const float* fin = p ? fB : fA;  float* fout = p ? fA : fB;
        const float* vin = p ? vB : vA;  float* vout = p ? vA : vB;
        layer_kernel<<<NBLK, 256, 0, stream>>>(qin, kin, fin, qout, kout, fout,
                                               vin, vout, sg, dirn_s, nbr_s, bins_s,
                                               resb, ridx, n2o,
                                               Wvec, wdir, dist_bias,
                                               Wo, W1, W2, Wg, Wq, Wk, Wv, l);
    }
    head_kernel<<<(RR+3)/4, 256, 0, stream>>>(resb, Wout, bout, out, RR);
}